// Round 11
// baseline (168.594 us; speedup 1.0000x reference)
//
#include <hip/hip_runtime.h>

typedef _Float16 half8  __attribute__((ext_vector_type(8)));
typedef _Float16 half4  __attribute__((ext_vector_type(4)));
typedef float    floatx4  __attribute__((ext_vector_type(4)));
typedef float    floatx16 __attribute__((ext_vector_type(16)));
typedef unsigned int uint4v __attribute__((ext_vector_type(4)));

constexpr int B_ = 2, S_ = 2048, D_ = 1024, H_ = 16, M_ = 4096;
constexpr int NR_ = B_ * H_ * S_;               // 65536 (b,h,s) rows
constexpr float QSCALE = 0.18033688011112042f;  // log2(e)/8
constexpr int KVB = 64;                         // kv tile
constexpr int HT = 16;                          // tiles per half (1024/64)

__device__ __forceinline__ void gload16(const void* g, void* l) {
  __builtin_amdgcn_global_load_lds((const __attribute__((address_space(1))) void*)g,
                                   (__attribute__((address_space(3))) void*)l, 16, 0, 0);
}

// ---------------------------------------------------------------------------
// cast fp32 -> fp16, 8 elems/thread
// ---------------------------------------------------------------------------
__global__ __launch_bounds__(256) void cast_f32_f16(const float* __restrict__ in,
                                                    _Float16* __restrict__ out, int n8) {
  int i = blockIdx.x * 256 + threadIdx.x;
  if (i >= n8) return;
  float4 a = reinterpret_cast<const float4*>(in)[2 * i];
  float4 b = reinterpret_cast<const float4*>(in)[2 * i + 1];
  half8 h;
  h[0] = (_Float16)a.x; h[1] = (_Float16)a.y; h[2] = (_Float16)a.z; h[3] = (_Float16)a.w;
  h[4] = (_Float16)b.x; h[5] = (_Float16)b.y; h[6] = (_Float16)b.z; h[7] = (_Float16)b.w;
  reinterpret_cast<half8*>(out)[i] = h;
}

// ---------------------------------------------------------------------------
// W[K][N] fp32 -> WT[N][K] fp16 (64x64 tiles). z selects {W_qkv, W_out}.
// ---------------------------------------------------------------------------
__global__ __launch_bounds__(256) void transpose_cast2(const float* __restrict__ W0,
                                                       _Float16* __restrict__ WT0,
                                                       const float* __restrict__ W1,
                                                       _Float16* __restrict__ WT1) {
  __shared__ float Ws[64][65];
  const int z = blockIdx.z;
  const int NW = z ? D_ : 3 * D_;
  if (blockIdx.x * 64 >= NW) return;
  const float* W = z ? W1 : W0;
  _Float16* WT = z ? WT1 : WT0;
  const int K = D_, N = NW;
  const int n0 = blockIdx.x * 64, k0 = blockIdx.y * 64;
  const int t = threadIdx.x;
#pragma unroll
  for (int i = 0; i < 4; i++) {
    int idx = t + 256 * i;
    int r = idx >> 4, c4 = idx & 15;
    float4 v = *reinterpret_cast<const float4*>(W + (size_t)(k0 + r) * N + n0 + c4 * 4);
    Ws[r][c4 * 4 + 0] = v.x; Ws[r][c4 * 4 + 1] = v.y;
    Ws[r][c4 * 4 + 2] = v.z; Ws[r][c4 * 4 + 3] = v.w;
  }
  __syncthreads();
#pragma unroll
  for (int i = 0; i < 2; i++) {
    int idx = t + 256 * i;
    int r = idx >> 3, ck = idx & 7;
    half8 h;
#pragma unroll
    for (int j = 0; j < 8; j++) h[j] = (_Float16)Ws[ck * 8 + j][r];
    *reinterpret_cast<half8*>(WT + (size_t)(n0 + r) * K + k0 + ck * 8) = h;
  }
}

// ---------------------------------------------------------------------------
// 256x192 fp16 MFMA GEMM, double-buffered, FINE-INTERLEAVED staging (R10).
// ---------------------------------------------------------------------------
__global__ __launch_bounds__(512, 2) void gemm256_mfma(
    const _Float16* __restrict__ A, const _Float16* __restrict__ BT,
    const float* __restrict__ bias, _Float16* __restrict__ Cout,
    int M, int N, int K, float scale_lo, int ncut) {
  extern __shared__ char smem[];   // 114688 B: As[2][32K] | Bs[2][24K]
  const int tid = threadIdx.x, w = tid >> 6, lane = tid & 63;
  const int wm = w >> 2, wn = w & 3;

  const int nwg = gridDim.x, cpx = nwg >> 3;
  const int wg = (blockIdx.x & 7) * cpx + (blockIdx.x >> 3);
  const int nbx = N / 192;
  const int bx = wg % nbx, by = wg / nbx;
  const int m0 = by * 256, n0 = bx * 192;

  const int NT = K >> 6;

  auto stageA1 = [&](int buf, int kt, int i) {
    const int k0 = kt * 64;
    char* Ad = smem + buf * 32768;
    int idx = tid + 512 * i;
    int r = idx >> 3, c = idx & 7, cs = c ^ (r & 7);
    gload16(A + (size_t)(m0 + r) * K + k0 + cs * 8, Ad + idx * 16);
  };
  auto stageB1 = [&](int buf, int kt, int i) {
    const int k0 = kt * 64;
    char* Bd = smem + 65536 + buf * 24576;
    int idx = tid + 512 * i;
    int r = idx >> 3, c = idx & 7, cs = c ^ (r & 7);
    gload16(BT + (size_t)(n0 + r) * K + k0 + cs * 8, Bd + idx * 16);
  };

  floatx4 acc[8][3] = {};

#pragma unroll
  for (int i = 0; i < 4; i++) stageA1(0, 0, i);
#pragma unroll
  for (int i = 0; i < 3; i++) stageB1(0, 0, i);

  for (int kt = 0; kt < NT; ++kt) {
    const int p = kt & 1;
    asm volatile("s_waitcnt vmcnt(0)" ::: "memory");
    __builtin_amdgcn_s_barrier();
    __builtin_amdgcn_sched_barrier(0);

    const char* Ab = smem + p * 32768;
    const char* Bb = smem + 65536 + p * 24576;
    const bool more = (kt + 1 < NT);
#pragma unroll
    for (int q = 0; q < 4; q++) {
      half8 af[2][2], bf[3][2];
#pragma unroll
      for (int e = 0; e < 2; e++)
#pragma unroll
        for (int ks = 0; ks < 2; ks++) {
          int row = wm * 128 + (2 * q + e) * 16 + (lane & 15);
          int ch = (ks * 4 + (lane >> 4)) ^ (row & 7);
          af[e][ks] = *reinterpret_cast<const half8*>(Ab + row * 128 + ch * 16);
        }
#pragma unroll
      for (int n = 0; n < 3; n++)
#pragma unroll
        for (int ks = 0; ks < 2; ks++) {
          int row = wn * 48 + n * 16 + (lane & 15);
          int ch = (ks * 4 + (lane >> 4)) ^ (row & 7);
          bf[n][ks] = *reinterpret_cast<const half8*>(Bb + row * 128 + ch * 16);
        }
      if (more) {
        if (q == 0)      { stageA1(p ^ 1, kt + 1, 0); stageA1(p ^ 1, kt + 1, 1); }
        else if (q == 1) { stageA1(p ^ 1, kt + 1, 2); stageA1(p ^ 1, kt + 1, 3); }
        else if (q == 2) { stageB1(p ^ 1, kt + 1, 0); stageB1(p ^ 1, kt + 1, 1); }
        else             { stageB1(p ^ 1, kt + 1, 2); }
      }
      __builtin_amdgcn_s_setprio(1);
#pragma unroll
      for (int ks = 0; ks < 2; ks++)
#pragma unroll
        for (int e = 0; e < 2; e++)
#pragma unroll
          for (int n = 0; n < 3; n++)
            acc[2 * q + e][n] = __builtin_amdgcn_mfma_f32_16x16x32_f16(
                af[e][ks], bf[n][ks], acc[2 * q + e][n], 0, 0, 0);
      __builtin_amdgcn_s_setprio(0);
    }
    __builtin_amdgcn_sched_barrier(0);
    __builtin_amdgcn_s_barrier();
  }

#pragma unroll
  for (int mf = 0; mf < 8; mf++)
#pragma unroll
    for (int n = 0; n < 3; n++) {
      int col = n0 + wn * 48 + n * 16 + (lane & 15);
      float bv = bias[col];
      float sc = (col < ncut) ? scale_lo : 1.0f;
#pragma unroll
      for (int reg = 0; reg < 4; reg++) {
        int row = m0 + wm * 128 + mf * 16 + (lane >> 4) * 4 + reg;
        Cout[(size_t)row * N + col] = (_Float16)((acc[mf][n][reg] + bv) * sc);
      }
    }
}

// ---------------------------------------------------------------------------
// fp16 MFMA GEMM, 128x128 tile (m97-class) — output projection
// ---------------------------------------------------------------------------
template <bool OUT_HALF>
__global__ __launch_bounds__(256) void gemm_mfma(const _Float16* __restrict__ A,
                                                 const _Float16* __restrict__ BT,
                                                 const float* __restrict__ bias,
                                                 void* __restrict__ Cout,
                                                 int M, int N, int K,
                                                 float scale_lo, int ncut) {
  __shared__ _Float16 As[128 * 64];
  __shared__ _Float16 Bs[128 * 64];
  const int t = threadIdx.x, w = t >> 6, lane = t & 63;
  const int m0 = blockIdx.y * 128, n0 = blockIdx.x * 128;
  const int wr = (w >> 1) * 64, wc = (w & 1) * 64;

  floatx4 acc[4][4] = {};

  for (int k0 = 0; k0 < K; k0 += 64) {
    __syncthreads();
#pragma unroll
    for (int i = 0; i < 4; i++) {
      int idx = t + 256 * i;
      int r = idx >> 3, c = idx & 7;
      int cs = c ^ (r & 7);
      gload16(A + (size_t)(m0 + r) * K + k0 + cs * 8, (char*)As + idx * 16);
      gload16(BT + (size_t)(n0 + r) * K + k0 + cs * 8, (char*)Bs + idx * 16);
    }
    __syncthreads();
#pragma unroll
    for (int ks = 0; ks < 2; ks++) {
      half8 af[4], bf[4];
#pragma unroll
      for (int r = 0; r < 4; r++) {
        int row = wr + r * 16 + (lane & 15);
        int ch = (ks * 4 + (lane >> 4)) ^ (row & 7);
        af[r] = *reinterpret_cast<const half8*>((const char*)As + row * 128 + ch * 16);
      }
#pragma unroll
      for (int c = 0; c < 4; c++) {
        int row = wc + c * 16 + (lane & 15);
        int ch = (ks * 4 + (lane >> 4)) ^ (row & 7);
        bf[c] = *reinterpret_cast<const half8*>((const char*)Bs + row * 128 + ch * 16);
      }
#pragma unroll
      for (int r = 0; r < 4; r++)
#pragma unroll
        for (int c = 0; c < 4; c++)
          acc[r][c] = __builtin_amdgcn_mfma_f32_16x16x32_f16(af[r], bf[c], acc[r][c], 0, 0, 0);
    }
  }

#pragma unroll
  for (int r = 0; r < 4; r++)
#pragma unroll
    for (int c = 0; c < 4; c++) {
      int col = n0 + wc + c * 16 + (lane & 15);
      float bv = bias[col];
      float sc = (col < ncut) ? scale_lo : 1.0f;
#pragma unroll
      for (int reg = 0; reg < 4; reg++) {
        int row = m0 + wr + r * 16 + (lane >> 4) * 4 + reg;
        float v = (acc[r][c][reg] + bv) * sc;
        if (OUT_HALF)
          reinterpret_cast<_Float16*>(Cout)[(size_t)row * N + col] = (_Float16)v;
        else
          reinterpret_cast<float*>(Cout)[(size_t)row * N + col] = v;
      }
    }
}

// ---------------------------------------------------------------------------
// V transpose: qkv[B*S][3D] fp16 (V slice) -> Vt[(b*H+h)*64 + d][S] fp16
// ---------------------------------------------------------------------------
__global__ __launch_bounds__(256) void v_transpose(const _Float16* __restrict__ qkv,
                                                   _Float16* __restrict__ Vt) {
  __shared__ _Float16 Vs[64][72];
  const int s0 = blockIdx.x * 64, bh = blockIdx.y;
  const int b = bh >> 4, h = bh & 15;
  const int t = threadIdx.x;
#pragma unroll
  for (int i = 0; i < 2; i++) {
    int idx = t + 256 * i;
    int r = idx >> 3, c = idx & 7;
    half8 v = *reinterpret_cast<const half8*>(
        qkv + (size_t)(b * S_ + s0 + r) * (3 * D_) + 2 * D_ + h * 64 + c * 8);
    *reinterpret_cast<half8*>(&Vs[r][c * 8]) = v;
  }
  __syncthreads();
#pragma unroll
  for (int i = 0; i < 2; i++) {
    int idx = t + 256 * i;
    int d = idx >> 3, c = idx & 7;
    half8 o;
#pragma unroll
    for (int j = 0; j < 8; j++) o[j] = Vs[c * 8 + j][d];
    *reinterpret_cast<half8*>(Vt + ((size_t)bh * 64 + d) * S_ + s0 + c * 8) = o;
  }
}

// ---------------------------------------------------------------------------
// Flash attention R11: V read DIRECT from global Vt (L2-resident, m169) into
// register fragments, software-pipelined pairs — no V LDS staging.
// K stays LDS-staged (double-buffered, 16 KiB total).
// vmcnt FIFO design: per tile, issue [V-pair0 (2 loads), K(tt+1) (2 gload_lds)]
// then vmcnt(4): drains K(tt), leaves the 4 new in flight. PV's compiler-
// managed V waits never drain K(tt+1) (issued before all ks>=1 pairs).
// max3 (T17) for score-max; tree rs-sum. launch_bounds(256,3) (no spill room
// for the +16 V-pipeline regs at the (256,4) 128-reg cap).
// ---------------------------------------------------------------------------
__global__ __launch_bounds__(256, 3) void flash_mfma(const _Float16* __restrict__ qkv,
                                                     const _Float16* __restrict__ Vt,
                                                     _Float16* __restrict__ Opart,
                                                     float* __restrict__ keys) {
  const int qt = blockIdx.x, h = blockIdx.y;
  const int b = blockIdx.z >> 1, sp = blockIdx.z & 1;
  const int t = threadIdx.x, w = t >> 6, lane = t & 63;
  const int lo = lane & 31, hi = lane >> 5;

  __shared__ _Float16 Ks[2][KVB * 64];    // [kk][d] rows 128B, chunk^(r&7); 16 KiB

  const int qrow = qt * 128 + w * 32 + lo;
  const _Float16* qbase = qkv + (size_t)(b * S_ + qrow) * (3 * D_) + h * 64;
  half8 qf[4];
#pragma unroll
  for (int kd = 0; kd < 4; kd++)
    qf[kd] = *reinterpret_cast<const half8*>(qbase + kd * 16 + hi * 8);
  asm volatile("" : "+v"(qf[0]), "+v"(qf[1]), "+v"(qf[2]), "+v"(qf[3]));

  const size_t kbase = (size_t)(b * S_) * (3 * D_) + D_ + h * 64;
  const size_t vbase = (size_t)(b * H_ + h) * 64 * S_;
  const int kvbase = sp * (S_ / 2);

  auto stageK = [&](int buf, int tile) {
    const int kv0 = kvbase + tile * KVB;
    const _Float16* kg = qkv + kbase + (size_t)kv0 * (3 * D_);
#pragma unroll
    for (int p = 0; p < 2; p++) {
      int idx = t + 256 * p;
      int r = idx >> 3, c = idx & 7, cs = c ^ (r & 7);
      gload16(kg + (size_t)r * (3 * D_) + cs * 8, (char*)&Ks[buf][0] + idx * 16);
    }
  };

  floatx16 o0, o1;
#pragma unroll
  for (int r = 0; r < 16; r++) { o0[r] = 0.f; o1[r] = 0.f; }
  float m = -1e30f, l = 0.f;

  stageK(0, 0);

  for (int tt = 0; tt < HT; ++tt) {
    const int cb = tt & 1;
    const int kv0 = kvbase + tt * KVB;
    const _Float16* vgl = Vt + vbase + kv0;

    // V pair for ks=0, issued BEFORE K prefetch (FIFO: its wait won't drain K)
    half8 va = *reinterpret_cast<const half8*>(vgl + (size_t)lo * S_ + hi * 8);
    half8 vb = *reinterpret_cast<const half8*>(vgl + (size_t)(lo + 32) * S_ + hi * 8);

    stageK(cb ^ 1, (tt + 1) & (HT - 1));
    asm volatile("s_waitcnt vmcnt(4)" ::: "memory");  // drain K(tt); keep va,vb,K(tt+1)
    __builtin_amdgcn_s_barrier();
    __builtin_amdgcn_sched_barrier(0);   // no ds_read hoist above the barrier

    // ---- S^T = K @ Q^T : lane holds q=lo
    const char* kb2 = (const char*)&Ks[cb][0];
    floatx16 s0v, s1v;
#pragma unroll
    for (int r = 0; r < 16; r++) { s0v[r] = 0.f; s1v[r] = 0.f; }
    __builtin_amdgcn_s_setprio(1);
#pragma unroll
    for (int kd = 0; kd < 4; kd++) {
      int r0 = lo, r1 = 32 + lo;
      half8 k0f = *reinterpret_cast<const half8*>(
          kb2 + r0 * 128 + (((kd * 2 + hi) ^ (r0 & 7)) * 16));
      half8 k1f = *reinterpret_cast<const half8*>(
          kb2 + r1 * 128 + (((kd * 2 + hi) ^ (r1 & 7)) * 16));
      s0v = __builtin_amdgcn_mfma_f32_32x32x16_f16(k0f, qf[kd], s0v, 0, 0, 0);
      s1v = __builtin_amdgcn_mfma_f32_32x32x16_f16(k1f, qf[kd], s1v, 0, 0, 0);
    }
    __builtin_amdgcn_s_setprio(0);

    // ---- online softmax (exp2 domain), defer-max THR=8; max3 tree
    float tm[16];
#pragma unroll
    for (int r = 0; r < 16; r++) tm[r] = fmaxf(s0v[r], s1v[r]);
    float u0 = fmaxf(fmaxf(tm[0], tm[1]), tm[2]);
    float u1 = fmaxf(fmaxf(tm[3], tm[4]), tm[5]);
    float u2 = fmaxf(fmaxf(tm[6], tm[7]), tm[8]);
    float u3 = fmaxf(fmaxf(tm[9], tm[10]), tm[11]);
    float u4 = fmaxf(fmaxf(tm[12], tm[13]), tm[14]);
    float pm = fmaxf(fmaxf(u0, u1), u2);
    pm = fmaxf(fmaxf(pm, u3), u4);
    pm = fmaxf(pm, tm[15]);
    pm = fmaxf(pm, __shfl_xor(pm, 32));
    if (!__all(pm <= m + 8.0f)) {
      float mn = fmaxf(m, pm);
      float al = __builtin_amdgcn_exp2f(m - mn);
      m = mn; l *= al;
#pragma unroll
      for (int r = 0; r < 16; r++) { o0[r] *= al; o1[r] *= al; }
    }
    float rr[16];
#pragma unroll
    for (int r = 0; r < 16; r++) {
      s0v[r] = __builtin_amdgcn_exp2f(s0v[r] - m);
      s1v[r] = __builtin_amdgcn_exp2f(s1v[r] - m);
      rr[r] = s0v[r] + s1v[r];
    }
#pragma unroll
    for (int st = 8; st >= 1; st >>= 1)
#pragma unroll
      for (int r = 0; r < st; r++) rr[r] += rr[r + st];
    float rs = rr[0];
    rs += __shfl_xor(rs, 32);
    l += rs;

    // ---- convert P to fp16 B-fragments (cvt_pk + permlane)
    half8 pf0a, pf0b, pf1a, pf1b;
    {
      unsigned a0 = __builtin_bit_cast(unsigned, __builtin_amdgcn_cvt_pkrtz(s0v[0], s0v[1]));
      unsigned b0 = __builtin_bit_cast(unsigned, __builtin_amdgcn_cvt_pkrtz(s0v[4], s0v[5]));
      unsigned a1 = __builtin_bit_cast(unsigned, __builtin_amdgcn_cvt_pkrtz(s0v[2], s0v[3]));
      unsigned b1 = __builtin_bit_cast(unsigned, __builtin_amdgcn_cvt_pkrtz(s0v[6], s0v[7]));
      asm("v_permlane32_swap_b32 %0, %1" : "+v"(a0), "+v"(b0));
      asm("v_permlane32_swap_b32 %0, %1" : "+v"(a1), "+v"(b1));
      uint4v u; u[0] = a0; u[1] = a1; u[2] = b0; u[3] = b1;
      pf0a = __builtin_bit_cast(half8, u);
      a0 = __builtin_bit_cast(unsigned, __builtin_amdgcn_cvt_pkrtz(s0v[8], s0v[9]));
      b0 = __builtin_bit_cast(unsigned, __builtin_amdgcn_cvt_pkrtz(s0v[12], s0v[13]));
      a1 = __builtin_bit_cast(unsigned, __builtin_amdgcn_cvt_pkrtz(s0v[10], s0v[11]));
      b1 = __builtin_bit_cast(unsigned, __builtin_amdgcn_cvt_pkrtz(s0v[14], s0v[15]));
      asm("v_permlane32_swap_b32 %0, %1" : "+v"(a0), "+v"(b0));
      asm("v_permlane32_swap_b32 %0, %1" : "+v"(a1), "+v"(b1));
      u[0] = a0; u[1] = a1; u[2] = b0; u[3] = b1;
      pf0b = __builtin_bit_cast(half8, u);
      a0 = __builtin_bit_cast(unsigned, __builtin_amdgcn_cvt_pkrtz(s1v[0], s1v[1]));
      b0 = __builtin_bit_cast(unsigned, __builtin_amdgcn_cvt_pkrtz(s1v[4], s1v[5]));
      a1 = __builtin_bit_cast(unsigned, __builtin_amdgcn_cvt_pkrtz(s1v[2], s1v[3]));
      b1 = __builtin_bit_cast(unsigned, __builtin_amdgcn_cvt_pkrtz(s1v[6], s1v[7]));
      asm("v_permlane32_swap_b32 %0, %1" : "+v"(a0), "+v"(b0));
      asm("v_permlane32_swap_b32 %0, %1" : "+v"(a1), "+v"(b1));
      u[0] = a0; u[1] = a1; u[2] = b0; u[3] = b1;
      pf1a = __builtin_bit_cast(half8, u);
      a0 = __builtin_bit_cast(unsigned, __builtin_amdgcn_cvt_pkrtz(s1v[8], s1v[9]));
      b0 = __builtin_bit_cast(unsigned, __builtin_amdgcn_cvt_pkrtz(s1v[12], s1v[13]));
      a1 = __builtin_bit_cast(unsigned, __builtin_amdgcn_cvt_pkrtz(s1v[10], s1v[11]));
      b1 = __builtin_bit_cast(unsigned, __builtin_amdgcn_cvt_pkrtz(s1v[14], s1v[15]));
      asm("v_permlane32_swap_b32 %0, %1" : "+v"(a0), "+v"(b0));
      asm("v_permlane32_swap_b32 %0, %1" : "+v"(a1), "+v"(b1));
      u[0] = a0; u[1] = a1; u[2] = b0; u[3] = b1;
      pf1b = __builtin_bit_cast(half8, u);
    }

    // ---- O^T += V^T @ P^T ; V fragments from global, software-pipelined
    __builtin_amdgcn_s_setprio(1);
#pragma unroll
    for (int ks = 0; ks < 4; ks++) {
      half8 pf = (ks == 0) ? pf0a : (ks == 1) ? pf0b : (ks == 2) ? pf1a : pf1b;
      half8 vna, vnb;
      if (ks < 3) {
        int off = (ks + 1) * 16 + hi * 8;
        vna = *reinterpret_cast<const half8*>(vgl + (size_t)lo * S_ + off);
        vnb = *reinterpret_cast<const half8*>(vgl + (size_t)(lo + 32) * S_ + off);
      }
      o0 = __builtin_amdgcn_mfma_f32_32x32x16_f16(va, pf, o0, 0, 0, 0);
      o1 = __builtin_amdgcn_mfma_f32_32x32x16_f16(vb, pf, o1, 0, 0, 0);
      if (ks < 3) { va = vna; vb = vnb; }
    }
    __builtin_amdgcn_s_setprio(0);

    __builtin_amdgcn_sched_barrier(0);   // no ds_read/load sink below the barrier
    __builtin_amdgcn_s_barrier();
  }

  float inv = 1.0f / l;
  const int gr = (b * H_ + h) * S_ + qrow;
  _Float16* ob = Opart + ((size_t)sp * NR_ + gr) * 64;
#pragma unroll
  for (int mt = 0; mt < 2; mt++)
#pragma unroll
    for (int rq = 0; rq < 4; rq++) {
      half4 v;
#pragma unroll
      for (int e = 0; e < 4; e++) v[e] = (_Float16)(((mt ? o1 : o0)[4 * rq + e]) * inv);
      *reinterpret_cast<half4*>(ob + 32 * mt + 8 * rq + 4 * hi) = v;
    }
  if (hi == 0) keys[sp * NR_ + gr] = m + __log2f(l);
}

// ---------------------------------------------------------------------------
// Combine the two KV-split halves: out = (w0*O0 + w1*O1)/(w0+w1), wi = 2^keyi
// ---------------------------------------------------------------------------
__global__ __launch_bounds__(256) void flash_combine(const _Float16* __restrict__ Opart,
                                                     const float* __restrict__ keys,
                                                     _Float16* __restrict__ attn_out) {
  const int gr = blockIdx.x * 256 + threadIdx.x;
  const float k0 = keys[gr], k1 = keys[NR_ + gr];
  const float mx = fmaxf(k0, k1);
  const float w0 = __builtin_amdgcn_exp2f(k0 - mx);
  const float w1 = __builtin_amdgcn_exp2f(k1 - mx);
  const float inv = 1.0f / (w0 + w1);
  const float a0 = w0 * inv, a1 = w1 * inv;
  const int bh = gr >> 11, qs = gr & 2047, b = bh >> 4, h = bh & 15;
  const half8* p0 = reinterpret_cast<const half8*>(Opart + (size_t)gr * 64);
  const half8* p1 = reinterpret_cast<const half8*>(Opart + ((size_t)NR_ + gr) * 64);
  half8* ob = reinterpret_cast<half8*>(
      attn_out + ((size_t)(b * S_ + qs)) * D_ + h * 64);
#pragma unroll
  for (int j = 0; j < 8; j++) {
    half8 x0 = p0[j], x1 = p1[j];
    half8 o;
#pragma unroll
    for (int e = 0; e < 8; e++)
      o[e] = (_Float16)(a0 * (float)x0[e] + a1 * (float)x1[e]);
    ob[j] = o;
  }
}

// ---------------------------------------------------------------------------
extern "C" void kernel_launch(void* const* d_in, const int* in_sizes, int n_in,
                              void* d_out, int out_size, void* d_ws, size_t ws_size,
                              hipStream_t stream) {
  const float* x     = (const float*)d_in[0];
  const float* W_qkv = (const float*)d_in[1];
  const float* b_qkv = (const float*)d_in[2];
  const float* W_out = (const float*)d_in[3];
  const float* b_out = (const float*)d_in[4];
  float* out = (float*)d_out;

  _Float16* xh    = (_Float16*)d_ws;
  _Float16* qkvh  = xh + (size_t)M_ * D_;
  _Float16* Vth   = qkvh + (size_t)M_ * 3 * D_;
  _Float16* WoT   = Vth + (size_t)B_ * H_ * 64 * S_;
  _Float16* WqT   = WoT + (size_t)D_ * D_;
  _Float16* Opart = WqT;                                  // alias (WqT dead by flash)
  float*    keys  = (float*)(Opart + (size_t)2 * NR_ * 64);
  _Float16* atth  = xh;                                   // alias (xh dead by combine)

  cast_f32_f16<<<(M_ * D_ / 8 + 255) / 256, 256, 0, stream>>>(x, xh, M_ * D_ / 8);
  transpose_cast2<<<dim3(3 * D_ / 64, D_ / 64, 2), 256, 0, stream>>>(
      W_qkv, WqT, W_out, WoT);

  gemm256_mfma<<<256, 512, 114688, stream>>>(
      xh, WqT, b_qkv, qkvh, M_, 3 * D_, D_, QSCALE, D_);

  v_transpose<<<dim3(S_ / 64, B_ * H_), 256, 0, stream>>>(qkvh, Vth);

  flash_mfma<<<dim3(S_ / 128, H_, B_ * 2), 256, 0, stream>>>(qkvh, Vth, Opart, keys);

  flash_combine<<<NR_ / 256, 256, 0, stream>>>(Opart, keys, atth);

  gemm_mfma<false><<<dim3(D_ / 128, M_ / 128), 256, 0, stream>>>(
      atth, WoT, b_out, out, M_, D_, D_, 1.0f, 0);
}

// Round 12
// 128.365 us; speedup vs baseline: 1.3134x; 1.3134x over previous
//
#include <hip/hip_runtime.h>

typedef _Float16 half8  __attribute__((ext_vector_type(8)));
typedef _Float16 half4  __attribute__((ext_vector_type(4)));
typedef float    floatx4  __attribute__((ext_vector_type(4)));
typedef float    floatx16 __attribute__((ext_vector_type(16)));
typedef unsigned int uint4v __attribute__((ext_vector_type(4)));

constexpr int B_ = 2, S_ = 2048, D_ = 1024, H_ = 16, M_ = 4096;
constexpr int NR_ = B_ * H_ * S_;               // 65536 (b,h,s) rows
constexpr float QSCALE = 0.18033688011112042f;  // log2(e)/8
constexpr int KVB = 64;                         // kv tile
constexpr int HT = 16;                          // tiles per half (1024/64)

__device__ __forceinline__ void gload16(const void* g, void* l) {
  __builtin_amdgcn_global_load_lds((const __attribute__((address_space(1))) void*)g,
                                   (__attribute__((address_space(3))) void*)l, 16, 0, 0);
}

// ---------------------------------------------------------------------------
// cast fp32 -> fp16, 8 elems/thread
// ---------------------------------------------------------------------------
__global__ __launch_bounds__(256) void cast_f32_f16(const float* __restrict__ in,
                                                    _Float16* __restrict__ out, int n8) {
  int i = blockIdx.x * 256 + threadIdx.x;
  if (i >= n8) return;
  float4 a = reinterpret_cast<const float4*>(in)[2 * i];
  float4 b = reinterpret_cast<const float4*>(in)[2 * i + 1];
  half8 h;
  h[0] = (_Float16)a.x; h[1] = (_Float16)a.y; h[2] = (_Float16)a.z; h[3] = (_Float16)a.w;
  h[4] = (_Float16)b.x; h[5] = (_Float16)b.y; h[6] = (_Float16)b.z; h[7] = (_Float16)b.w;
  reinterpret_cast<half8*>(out)[i] = h;
}

// ---------------------------------------------------------------------------
// W[K][N] fp32 -> WT[N][K] fp16 (64x64 tiles). z selects {W_qkv, W_out}.
// ---------------------------------------------------------------------------
__global__ __launch_bounds__(256) void transpose_cast2(const float* __restrict__ W0,
                                                       _Float16* __restrict__ WT0,
                                                       const float* __restrict__ W1,
                                                       _Float16* __restrict__ WT1) {
  __shared__ float Ws[64][65];
  const int z = blockIdx.z;
  const int NW = z ? D_ : 3 * D_;
  if (blockIdx.x * 64 >= NW) return;
  const float* W = z ? W1 : W0;
  _Float16* WT = z ? WT1 : WT0;
  const int K = D_, N = NW;
  const int n0 = blockIdx.x * 64, k0 = blockIdx.y * 64;
  const int t = threadIdx.x;
#pragma unroll
  for (int i = 0; i < 4; i++) {
    int idx = t + 256 * i;
    int r = idx >> 4, c4 = idx & 15;
    float4 v = *reinterpret_cast<const float4*>(W + (size_t)(k0 + r) * N + n0 + c4 * 4);
    Ws[r][c4 * 4 + 0] = v.x; Ws[r][c4 * 4 + 1] = v.y;
    Ws[r][c4 * 4 + 2] = v.z; Ws[r][c4 * 4 + 3] = v.w;
  }
  __syncthreads();
#pragma unroll
  for (int i = 0; i < 2; i++) {
    int idx = t + 256 * i;
    int r = idx >> 3, ck = idx & 7;
    half8 h;
#pragma unroll
    for (int j = 0; j < 8; j++) h[j] = (_Float16)Ws[ck * 8 + j][r];
    *reinterpret_cast<half8*>(WT + (size_t)(n0 + r) * K + k0 + ck * 8) = h;
  }
}

// ---------------------------------------------------------------------------
// 256x192 fp16 MFMA GEMM, double-buffered, fine-interleaved staging (R10).
// ---------------------------------------------------------------------------
__global__ __launch_bounds__(512, 2) void gemm256_mfma(
    const _Float16* __restrict__ A, const _Float16* __restrict__ BT,
    const float* __restrict__ bias, _Float16* __restrict__ Cout,
    int M, int N, int K, float scale_lo, int ncut) {
  extern __shared__ char smem[];   // 114688 B: As[2][32K] | Bs[2][24K]
  const int tid = threadIdx.x, w = tid >> 6, lane = tid & 63;
  const int wm = w >> 2, wn = w & 3;

  const int nwg = gridDim.x, cpx = nwg >> 3;
  const int wg = (blockIdx.x & 7) * cpx + (blockIdx.x >> 3);
  const int nbx = N / 192;
  const int bx = wg % nbx, by = wg / nbx;
  const int m0 = by * 256, n0 = bx * 192;

  const int NT = K >> 6;

  auto stageA1 = [&](int buf, int kt, int i) {
    const int k0 = kt * 64;
    char* Ad = smem + buf * 32768;
    int idx = tid + 512 * i;
    int r = idx >> 3, c = idx & 7, cs = c ^ (r & 7);
    gload16(A + (size_t)(m0 + r) * K + k0 + cs * 8, Ad + idx * 16);
  };
  auto stageB1 = [&](int buf, int kt, int i) {
    const int k0 = kt * 64;
    char* Bd = smem + 65536 + buf * 24576;
    int idx = tid + 512 * i;
    int r = idx >> 3, c = idx & 7, cs = c ^ (r & 7);
    gload16(BT + (size_t)(n0 + r) * K + k0 + cs * 8, Bd + idx * 16);
  };

  floatx4 acc[8][3] = {};

#pragma unroll
  for (int i = 0; i < 4; i++) stageA1(0, 0, i);
#pragma unroll
  for (int i = 0; i < 3; i++) stageB1(0, 0, i);

  for (int kt = 0; kt < NT; ++kt) {
    const int p = kt & 1;
    asm volatile("s_waitcnt vmcnt(0)" ::: "memory");
    __builtin_amdgcn_s_barrier();
    __builtin_amdgcn_sched_barrier(0);

    const char* Ab = smem + p * 32768;
    const char* Bb = smem + 65536 + p * 24576;
    const bool more = (kt + 1 < NT);
#pragma unroll
    for (int q = 0; q < 4; q++) {
      half8 af[2][2], bf[3][2];
#pragma unroll
      for (int e = 0; e < 2; e++)
#pragma unroll
        for (int ks = 0; ks < 2; ks++) {
          int row = wm * 128 + (2 * q + e) * 16 + (lane & 15);
          int ch = (ks * 4 + (lane >> 4)) ^ (row & 7);
          af[e][ks] = *reinterpret_cast<const half8*>(Ab + row * 128 + ch * 16);
        }
#pragma unroll
      for (int n = 0; n < 3; n++)
#pragma unroll
        for (int ks = 0; ks < 2; ks++) {
          int row = wn * 48 + n * 16 + (lane & 15);
          int ch = (ks * 4 + (lane >> 4)) ^ (row & 7);
          bf[n][ks] = *reinterpret_cast<const half8*>(Bb + row * 128 + ch * 16);
        }
      if (more) {
        if (q == 0)      { stageA1(p ^ 1, kt + 1, 0); stageA1(p ^ 1, kt + 1, 1); }
        else if (q == 1) { stageA1(p ^ 1, kt + 1, 2); stageA1(p ^ 1, kt + 1, 3); }
        else if (q == 2) { stageB1(p ^ 1, kt + 1, 0); stageB1(p ^ 1, kt + 1, 1); }
        else             { stageB1(p ^ 1, kt + 1, 2); }
      }
      __builtin_amdgcn_s_setprio(1);
#pragma unroll
      for (int ks = 0; ks < 2; ks++)
#pragma unroll
        for (int e = 0; e < 2; e++)
#pragma unroll
          for (int n = 0; n < 3; n++)
            acc[2 * q + e][n] = __builtin_amdgcn_mfma_f32_16x16x32_f16(
                af[e][ks], bf[n][ks], acc[2 * q + e][n], 0, 0, 0);
      __builtin_amdgcn_s_setprio(0);
    }
    __builtin_amdgcn_sched_barrier(0);
    __builtin_amdgcn_s_barrier();
  }

#pragma unroll
  for (int mf = 0; mf < 8; mf++)
#pragma unroll
    for (int n = 0; n < 3; n++) {
      int col = n0 + wn * 48 + n * 16 + (lane & 15);
      float bv = bias[col];
      float sc = (col < ncut) ? scale_lo : 1.0f;
#pragma unroll
      for (int reg = 0; reg < 4; reg++) {
        int row = m0 + wm * 128 + mf * 16 + (lane >> 4) * 4 + reg;
        Cout[(size_t)row * N + col] = (_Float16)((acc[mf][n][reg] + bv) * sc);
      }
    }
}

// ---------------------------------------------------------------------------
// 128x128 fp16 MFMA GEMM (output projection), fine-interleaved staging,
// fp32 out. 256 thr = 4 waves (2x2, 64x64 each); BK=64; 64 KiB LDS dbuf.
// Grid (4096/128)x(1024/128) = 32x8 = 256 blocks = full CU fill, 2 blocks/CU.
// Same fence/vmcnt skeleton as gemm256 (race-proven R8-R10).
// ---------------------------------------------------------------------------
__global__ __launch_bounds__(256, 2) void gemm128_mfma(
    const _Float16* __restrict__ A, const _Float16* __restrict__ BT,
    const float* __restrict__ bias, float* __restrict__ Cout,
    int M, int N, int K) {
  extern __shared__ char smem[];   // 65536 B: As[2][16K] | Bs[2][16K]
  const int tid = threadIdx.x, w = tid >> 6, lane = tid & 63;
  const int wm = w >> 1, wn = w & 1;

  const int nwg = gridDim.x, cpx = nwg >> 3;
  const int wg = (blockIdx.x & 7) * cpx + (blockIdx.x >> 3);
  const int nbx = N >> 7;
  const int bx = wg % nbx, by = wg / nbx;
  const int m0 = by * 128, n0 = bx * 128;

  const int NT = K >> 6;

  auto stageA1 = [&](int buf, int kt, int i) {   // i in 0..3
    const int k0 = kt * 64;
    char* Ad = smem + buf * 16384;
    int idx = tid + 256 * i;
    int r = idx >> 3, c = idx & 7, cs = c ^ (r & 7);
    gload16(A + (size_t)(m0 + r) * K + k0 + cs * 8, Ad + idx * 16);
  };
  auto stageB1 = [&](int buf, int kt, int i) {   // i in 0..3
    const int k0 = kt * 64;
    char* Bd = smem + 32768 + buf * 16384;
    int idx = tid + 256 * i;
    int r = idx >> 3, c = idx & 7, cs = c ^ (r & 7);
    gload16(BT + (size_t)(n0 + r) * K + k0 + cs * 8, Bd + idx * 16);
  };

  floatx4 acc[4][4] = {};

#pragma unroll
  for (int i = 0; i < 4; i++) stageA1(0, 0, i);
#pragma unroll
  for (int i = 0; i < 4; i++) stageB1(0, 0, i);

  for (int kt = 0; kt < NT; ++kt) {
    const int p = kt & 1;
    asm volatile("s_waitcnt vmcnt(0)" ::: "memory");
    __builtin_amdgcn_s_barrier();
    __builtin_amdgcn_sched_barrier(0);

    const char* Ab = smem + p * 16384;
    const char* Bb = smem + 32768 + p * 16384;
    const bool more = (kt + 1 < NT);

    // hoist B fragments once per K-tile (reused by all 4 m-frags)
    half8 bf[4][2];
#pragma unroll
    for (int n = 0; n < 4; n++)
#pragma unroll
      for (int ks = 0; ks < 2; ks++) {
        int row = wn * 64 + n * 16 + (lane & 15);
        int ch = (ks * 4 + (lane >> 4)) ^ (row & 7);
        bf[n][ks] = *reinterpret_cast<const half8*>(Bb + row * 128 + ch * 16);
      }

#pragma unroll
    for (int q = 0; q < 4; q++) {
      half8 af[2];
#pragma unroll
      for (int ks = 0; ks < 2; ks++) {
        int row = wm * 64 + q * 16 + (lane & 15);
        int ch = (ks * 4 + (lane >> 4)) ^ (row & 7);
        af[ks] = *reinterpret_cast<const half8*>(Ab + row * 128 + ch * 16);
      }
      if (more) {
        if (q == 0)      { stageA1(p ^ 1, kt + 1, 0); stageA1(p ^ 1, kt + 1, 1); }
        else if (q == 1) { stageA1(p ^ 1, kt + 1, 2); stageA1(p ^ 1, kt + 1, 3); }
        else if (q == 2) { stageB1(p ^ 1, kt + 1, 0); stageB1(p ^ 1, kt + 1, 1); }
        else             { stageB1(p ^ 1, kt + 1, 2); stageB1(p ^ 1, kt + 1, 3); }
      }
      __builtin_amdgcn_s_setprio(1);
#pragma unroll
      for (int ks = 0; ks < 2; ks++)
#pragma unroll
        for (int n = 0; n < 4; n++)
          acc[q][n] = __builtin_amdgcn_mfma_f32_16x16x32_f16(
              af[ks], bf[n][ks], acc[q][n], 0, 0, 0);
      __builtin_amdgcn_s_setprio(0);
    }
    __builtin_amdgcn_sched_barrier(0);
    __builtin_amdgcn_s_barrier();
  }

#pragma unroll
  for (int q = 0; q < 4; q++)
#pragma unroll
    for (int n = 0; n < 4; n++) {
      int col = n0 + wn * 64 + n * 16 + (lane & 15);
      float bv = bias[col];
#pragma unroll
      for (int reg = 0; reg < 4; reg++) {
        int row = m0 + wm * 64 + q * 16 + (lane >> 4) * 4 + reg;
        Cout[(size_t)row * N + col] = acc[q][n][reg] + bv;
      }
    }
}

// ---------------------------------------------------------------------------
// V transpose: qkv[B*S][3D] fp16 (V slice) -> Vt[(b*H+h)*64 + d][S] fp16
// ---------------------------------------------------------------------------
__global__ __launch_bounds__(256) void v_transpose(const _Float16* __restrict__ qkv,
                                                   _Float16* __restrict__ Vt) {
  __shared__ _Float16 Vs[64][72];
  const int s0 = blockIdx.x * 64, bh = blockIdx.y;
  const int b = bh >> 4, h = bh & 15;
  const int t = threadIdx.x;
#pragma unroll
  for (int i = 0; i < 2; i++) {
    int idx = t + 256 * i;
    int r = idx >> 3, c = idx & 7;
    half8 v = *reinterpret_cast<const half8*>(
        qkv + (size_t)(b * S_ + s0 + r) * (3 * D_) + 2 * D_ + h * 64 + c * 8);
    *reinterpret_cast<half8*>(&Vs[r][c * 8]) = v;
  }
  __syncthreads();
#pragma unroll
  for (int i = 0; i < 2; i++) {
    int idx = t + 256 * i;
    int d = idx >> 3, c = idx & 7;
    half8 o;
#pragma unroll
    for (int j = 0; j < 8; j++) o[j] = Vs[c * 8 + j][d];
    *reinterpret_cast<half8*>(Vt + ((size_t)bh * 64 + d) * S_ + s0 + c * 8) = o;
  }
}

// ---------------------------------------------------------------------------
// Flash attention — R10 race-proven structure (LDS-staged K AND V, KVB=64
// double-buffered, KV-SPLIT x2, counted vmcnt(4)) + R11's safe VALU trims
// (fmax tree -> v_max3 fusion, tree rs-sum). R11's direct-global V REVERTED
// (uncoalesced per-lane fragments: 64 cache lines/instr — m169 misapplied).
// ---------------------------------------------------------------------------
__global__ __launch_bounds__(256, 4) void flash_mfma(const _Float16* __restrict__ qkv,
                                                     const _Float16* __restrict__ Vt,
                                                     _Float16* __restrict__ Opart,
                                                     float* __restrict__ keys) {
  const int qt = blockIdx.x, h = blockIdx.y;
  const int b = blockIdx.z >> 1, sp = blockIdx.z & 1;
  const int t = threadIdx.x, w = t >> 6, lane = t & 63;
  const int lo = lane & 31, hi = lane >> 5;

  __shared__ _Float16 Ks[2][KVB * 64];    // [kk][d] rows 128B, chunk^(r&7)
  __shared__ _Float16 Vts[2][64 * KVB];   // [d][kk] rows 128B, chunk^(r&7)

  const int qrow = qt * 128 + w * 32 + lo;
  const _Float16* qbase = qkv + (size_t)(b * S_ + qrow) * (3 * D_) + h * 64;
  half8 qf[4];
#pragma unroll
  for (int kd = 0; kd < 4; kd++)
    qf[kd] = *reinterpret_cast<const half8*>(qbase + kd * 16 + hi * 8);
  asm volatile("" : "+v"(qf[0]), "+v"(qf[1]), "+v"(qf[2]), "+v"(qf[3]));

  const size_t kbase = (size_t)(b * S_) * (3 * D_) + D_ + h * 64;
  const size_t vbase = (size_t)(b * H_ + h) * 64 * S_;
  const int kvbase = sp * (S_ / 2);

  auto stage = [&](int buf, int tile) {
    const int kv0 = kvbase + tile * KVB;
    const _Float16* kg = qkv + kbase + (size_t)kv0 * (3 * D_);
#pragma unroll
    for (int p = 0; p < 2; p++) {
      int idx = t + 256 * p;
      int r = idx >> 3, c = idx & 7, cs = c ^ (r & 7);
      gload16(kg + (size_t)r * (3 * D_) + cs * 8, (char*)&Ks[buf][0] + idx * 16);
    }
    const _Float16* vg = Vt + vbase + kv0;
#pragma unroll
    for (int p = 0; p < 2; p++) {
      int idx = t + 256 * p;
      int r = idx >> 3, c = idx & 7, cs = c ^ (r & 7);
      gload16(vg + (size_t)r * S_ + cs * 8, (char*)&Vts[buf][0] + idx * 16);
    }
  };

  floatx16 o0, o1;
#pragma unroll
  for (int r = 0; r < 16; r++) { o0[r] = 0.f; o1[r] = 0.f; }
  float m = -1e30f, l = 0.f;

  stage(0, 0);

  for (int tt = 0; tt < HT; ++tt) {
    const int cb = tt & 1;
    stage(cb ^ 1, (tt + 1) & (HT - 1));
    asm volatile("s_waitcnt vmcnt(4)" ::: "memory");
    __builtin_amdgcn_s_barrier();
    __builtin_amdgcn_sched_barrier(0);   // no ds_read hoist above the barrier

    // ---- S^T = K @ Q^T : lane holds q=lo
    const char* kb2 = (const char*)&Ks[cb][0];
    floatx16 s0v, s1v;
#pragma unroll
    for (int r = 0; r < 16; r++) { s0v[r] = 0.f; s1v[r] = 0.f; }
    __builtin_amdgcn_s_setprio(1);
#pragma unroll
    for (int kd = 0; kd < 4; kd++) {
      int r0 = lo, r1 = 32 + lo;
      half8 k0f = *reinterpret_cast<const half8*>(
          kb2 + r0 * 128 + (((kd * 2 + hi) ^ (r0 & 7)) * 16));
      half8 k1f = *reinterpret_cast<const half8*>(
          kb2 + r1 * 128 + (((kd * 2 + hi) ^ (r1 & 7)) * 16));
      s0v = __builtin_amdgcn_mfma_f32_32x32x16_f16(k0f, qf[kd], s0v, 0, 0, 0);
      s1v = __builtin_amdgcn_mfma_f32_32x32x16_f16(k1f, qf[kd], s1v, 0, 0, 0);
    }
    __builtin_amdgcn_s_setprio(0);

    // ---- online softmax (exp2 domain), defer-max THR=8; max3 tree
    float tm[16];
#pragma unroll
    for (int r = 0; r < 16; r++) tm[r] = fmaxf(s0v[r], s1v[r]);
    float u0 = fmaxf(fmaxf(tm[0], tm[1]), tm[2]);
    float u1 = fmaxf(fmaxf(tm[3], tm[4]), tm[5]);
    float u2 = fmaxf(fmaxf(tm[6], tm[7]), tm[8]);
    float u3 = fmaxf(fmaxf(tm[9], tm[10]), tm[11]);
    float u4 = fmaxf(fmaxf(tm[12], tm[13]), tm[14]);
    float pm = fmaxf(fmaxf(u0, u1), u2);
    pm = fmaxf(fmaxf(pm, u3), u4);
    pm = fmaxf(pm, tm[15]);
    pm = fmaxf(pm, __shfl_xor(pm, 32));
    if (!__all(pm <= m + 8.0f)) {
      float mn = fmaxf(m, pm);
      float al = __builtin_amdgcn_exp2f(m - mn);
      m = mn; l *= al;
#pragma unroll
      for (int r = 0; r < 16; r++) { o0[r] *= al; o1[r] *= al; }
    }
    float rr[16];
#pragma unroll
    for (int r = 0; r < 16; r++) {
      s0v[r] = __builtin_amdgcn_exp2f(s0v[r] - m);
      s1v[r] = __builtin_amdgcn_exp2f(s1v[r] - m);
      rr[r] = s0v[r] + s1v[r];
    }
#pragma unroll
    for (int st = 8; st >= 1; st >>= 1)
#pragma unroll
      for (int r = 0; r < st; r++) rr[r] += rr[r + st];
    float rs = rr[0];
    rs += __shfl_xor(rs, 32);
    l += rs;

    // ---- convert P to fp16 B-fragments (cvt_pk + permlane)
    half8 pf0a, pf0b, pf1a, pf1b;
    {
      unsigned a0 = __builtin_bit_cast(unsigned, __builtin_amdgcn_cvt_pkrtz(s0v[0], s0v[1]));
      unsigned b0 = __builtin_bit_cast(unsigned, __builtin_amdgcn_cvt_pkrtz(s0v[4], s0v[5]));
      unsigned a1 = __builtin_bit_cast(unsigned, __builtin_amdgcn_cvt_pkrtz(s0v[2], s0v[3]));
      unsigned b1 = __builtin_bit_cast(unsigned, __builtin_amdgcn_cvt_pkrtz(s0v[6], s0v[7]));
      asm("v_permlane32_swap_b32 %0, %1" : "+v"(a0), "+v"(b0));
      asm("v_permlane32_swap_b32 %0, %1" : "+v"(a1), "+v"(b1));
      uint4v u; u[0] = a0; u[1] = a1; u[2] = b0; u[3] = b1;
      pf0a = __builtin_bit_cast(half8, u);
      a0 = __builtin_bit_cast(unsigned, __builtin_amdgcn_cvt_pkrtz(s0v[8], s0v[9]));
      b0 = __builtin_bit_cast(unsigned, __builtin_amdgcn_cvt_pkrtz(s0v[12], s0v[13]));
      a1 = __builtin_bit_cast(unsigned, __builtin_amdgcn_cvt_pkrtz(s0v[10], s0v[11]));
      b1 = __builtin_bit_cast(unsigned, __builtin_amdgcn_cvt_pkrtz(s0v[14], s0v[15]));
      asm("v_permlane32_swap_b32 %0, %1" : "+v"(a0), "+v"(b0));
      asm("v_permlane32_swap_b32 %0, %1" : "+v"(a1), "+v"(b1));
      u[0] = a0; u[1] = a1; u[2] = b0; u[3] = b1;
      pf0b = __builtin_bit_cast(half8, u);
      a0 = __builtin_bit_cast(unsigned, __builtin_amdgcn_cvt_pkrtz(s1v[0], s1v[1]));
      b0 = __builtin_bit_cast(unsigned, __builtin_amdgcn_cvt_pkrtz(s1v[4], s1v[5]));
      a1 = __builtin_bit_cast(unsigned, __builtin_amdgcn_cvt_pkrtz(s1v[2], s1v[3]));
      b1 = __builtin_bit_cast(unsigned, __builtin_amdgcn_cvt_pkrtz(s1v[6], s1v[7]));
      asm("v_permlane32_swap_b32 %0, %1" : "+v"(a0), "+v"(b0));
      asm("v_permlane32_swap_b32 %0, %1" : "+v"(a1), "+v"(b1));
      u[0] = a0; u[1] = a1; u[2] = b0; u[3] = b1;
      pf1a = __builtin_bit_cast(half8, u);
      a0 = __builtin_bit_cast(unsigned, __builtin_amdgcn_cvt_pkrtz(s1v[8], s1v[9]));
      b0 = __builtin_bit_cast(unsigned, __builtin_amdgcn_cvt_pkrtz(s1v[12], s1v[13]));
      a1 = __builtin_bit_cast(unsigned, __builtin_amdgcn_cvt_pkrtz(s1v[10], s1v[11]));
      b1 = __builtin_bit_cast(unsigned, __builtin_amdgcn_cvt_pkrtz(s1v[14], s1v[15]));
      asm("v_permlane32_swap_b32 %0, %1" : "+v"(a0), "+v"(b0));
      asm("v_permlane32_swap_b32 %0, %1" : "+v"(a1), "+v"(b1));
      u[0] = a0; u[1] = a1; u[2] = b0; u[3] = b1;
      pf1b = __builtin_bit_cast(half8, u);
    }

    // ---- O^T += V^T @ P^T ; V from LDS (coalesced staging, swizzled reads)
    const char* vb2 = (const char*)&Vts[cb][0];
    __builtin_amdgcn_s_setprio(1);
#pragma unroll
    for (int ks = 0; ks < 4; ks++) {
      half8 pf = (ks == 0) ? pf0a : (ks == 1) ? pf0b : (ks == 2) ? pf1a : pf1b;
      const int ch = ks * 2 + hi;
      half8 vf0 = *reinterpret_cast<const half8*>(vb2 + lo * 128 + ((ch ^ (lo & 7)) * 16));
      half8 vf1 = *reinterpret_cast<const half8*>(vb2 + (lo + 32) * 128 + ((ch ^ (lo & 7)) * 16));
      o0 = __builtin_amdgcn_mfma_f32_32x32x16_f16(vf0, pf, o0, 0, 0, 0);
      o1 = __builtin_amdgcn_mfma_f32_32x32x16_f16(vf1, pf, o1, 0, 0, 0);
    }
    __builtin_amdgcn_s_setprio(0);

    __builtin_amdgcn_sched_barrier(0);   // no ds_read sink below the barrier
    __builtin_amdgcn_s_barrier();
  }

  float inv = 1.0f / l;
  const int gr = (b * H_ + h) * S_ + qrow;
  _Float16* ob = Opart + ((size_t)sp * NR_ + gr) * 64;
#pragma unroll
  for (int mt = 0; mt < 2; mt++)
#pragma unroll
    for (int rq = 0; rq < 4; rq++) {
      half4 v;
#pragma unroll
      for (int e = 0; e < 4; e++) v[e] = (_Float16)(((mt ? o1 : o0)[4 * rq + e]) * inv);
      *reinterpret_cast<half4*>(ob + 32 * mt + 8 * rq + 4 * hi) = v;
    }
  if (hi == 0) keys[sp * NR_ + gr] = m + __log2f(l);
}

// ---------------------------------------------------------------------------
// Combine the two KV-split halves: out = (w0*O0 + w1*O1)/(w0+w1), wi = 2^keyi
// ---------------------------------------------------------------------------
__global__ __launch_bounds__(256) void flash_combine(const _Float16* __restrict__ Opart,
                                                     const float* __restrict__ keys,
                                                     _Float16* __restrict__ attn_out) {
  const int gr = blockIdx.x * 256 + threadIdx.x;
  const float k0 = keys[gr], k1 = keys[NR_ + gr];
  const float mx = fmaxf(k0, k1);
  const float w0 = __builtin_amdgcn_exp2f(k0 - mx);
  const float w1 = __builtin_amdgcn_exp2f(k1 - mx);
  const float inv = 1.0f / (w0 + w1);
  const float a0 = w0 * inv, a1 = w1 * inv;
  const int bh = gr >> 11, qs = gr & 2047, b = bh >> 4, h = bh & 15;
  const half8* p0 = reinterpret_cast<const half8*>(Opart + (size_t)gr * 64);
  const half8* p1 = reinterpret_cast<const half8*>(Opart + ((size_t)NR_ + gr) * 64);
  half8* ob = reinterpret_cast<half8*>(
      attn_out + ((size_t)(b * S_ + qs)) * D_ + h * 64);
#pragma unroll
  for (int j = 0; j < 8; j++) {
    half8 x0 = p0[j], x1 = p1[j];
    half8 o;
#pragma unroll
    for (int e = 0; e < 8; e++)
      o[e] = (_Float16)(a0 * (float)x0[e] + a1 * (float)x1[e]);
    ob[j] = o;
  }
}

// ---------------------------------------------------------------------------
extern "C" void kernel_launch(void* const* d_in, const int* in_sizes, int n_in,
                              void* d_out, int out_size, void* d_ws, size_t ws_size,
                              hipStream_t stream) {
  const float* x     = (const float*)d_in[0];
  const float* W_qkv = (const float*)d_in[1];
  const float* b_qkv = (const float*)d_in[2];
  const float* W_out = (const float*)d_in[3];
  const float* b_out = (const float*)d_in[4];
  float* out = (float*)d_out;

  _Float16* xh    = (_Float16*)d_ws;
  _Float16* qkvh  = xh + (size_t)M_ * D_;
  _Float16* Vth   = qkvh + (size_t)M_ * 3 * D_;
  _Float16* WoT   = Vth + (size_t)B_ * H_ * 64 * S_;
  _Float16* WqT   = WoT + (size_t)D_ * D_;
  _Float16* Opart = WqT;                                  // alias (WqT dead by flash)
  float*    keys  = (float*)(Opart + (size_t)2 * NR_ * 64);
  _Float16* atth  = xh;                                   // alias (xh dead by combine)

  cast_f32_f16<<<(M_ * D_ / 8 + 255) / 256, 256, 0, stream>>>(x, xh, M_ * D_ / 8);
  transpose_cast2<<<dim3(3 * D_ / 64, D_ / 64, 2), 256, 0, stream>>>(
      W_qkv, WqT, W_out, WoT);

  gemm256_mfma<<<256, 512, 114688, stream>>>(
      xh, WqT, b_qkv, qkvh, M_, 3 * D_, D_, QSCALE, D_);

  v_transpose<<<dim3(S_ / 64, B_ * H_), 256, 0, stream>>>(qkvh, Vth);

  flash_mfma<<<dim3(S_ / 128, H_, B_ * 2), 256, 0, stream>>>(qkvh, Vth, Opart, keys);

  flash_combine<<<NR_ / 256, 256, 0, stream>>>(Opart, keys, atth);

  // output projection: fine-interleaved 128x128, grid 32x8 = 256 = full fill
  gemm128_mfma<<<256, 256, 65536, stream>>>(
      atth, WoT, b_out, out, M_, D_, D_);
}

// Round 13
// 126.469 us; speedup vs baseline: 1.3331x; 1.0150x over previous
//
#include <hip/hip_runtime.h>

typedef _Float16 half8  __attribute__((ext_vector_type(8)));
typedef _Float16 half4  __attribute__((ext_vector_type(4)));
typedef float    floatx4  __attribute__((ext_vector_type(4)));
typedef float    floatx16 __attribute__((ext_vector_type(16)));
typedef unsigned int uint4v __attribute__((ext_vector_type(4)));

constexpr int B_ = 2, S_ = 2048, D_ = 1024, H_ = 16, M_ = 4096;
constexpr int NR_ = B_ * H_ * S_;               // 65536 (b,h,s) rows
constexpr float QSCALE = 0.18033688011112042f;  // log2(e)/8
constexpr int KVB = 64;                         // kv tile
constexpr int HT = 16;                          // tiles per half (1024/64)

__device__ __forceinline__ void gload16(const void* g, void* l) {
  __builtin_amdgcn_global_load_lds((const __attribute__((address_space(1))) void*)g,
                                   (__attribute__((address_space(3))) void*)l, 16, 0, 0);
}

// ---------------------------------------------------------------------------
// cast fp32 -> fp16, 8 elems/thread
// ---------------------------------------------------------------------------
__global__ __launch_bounds__(256) void cast_f32_f16(const float* __restrict__ in,
                                                    _Float16* __restrict__ out, int n8) {
  int i = blockIdx.x * 256 + threadIdx.x;
  if (i >= n8) return;
  float4 a = reinterpret_cast<const float4*>(in)[2 * i];
  float4 b = reinterpret_cast<const float4*>(in)[2 * i + 1];
  half8 h;
  h[0] = (_Float16)a.x; h[1] = (_Float16)a.y; h[2] = (_Float16)a.z; h[3] = (_Float16)a.w;
  h[4] = (_Float16)b.x; h[5] = (_Float16)b.y; h[6] = (_Float16)b.z; h[7] = (_Float16)b.w;
  reinterpret_cast<half8*>(out)[i] = h;
}

// ---------------------------------------------------------------------------
// W[K][N] fp32 -> WT[N][K] fp16 (64x64 tiles). z selects {W_qkv, W_out}.
// ---------------------------------------------------------------------------
__global__ __launch_bounds__(256) void transpose_cast2(const float* __restrict__ W0,
                                                       _Float16* __restrict__ WT0,
                                                       const float* __restrict__ W1,
                                                       _Float16* __restrict__ WT1) {
  __shared__ float Ws[64][65];
  const int z = blockIdx.z;
  const int NW = z ? D_ : 3 * D_;
  if (blockIdx.x * 64 >= NW) return;
  const float* W = z ? W1 : W0;
  _Float16* WT = z ? WT1 : WT0;
  const int K = D_, N = NW;
  const int n0 = blockIdx.x * 64, k0 = blockIdx.y * 64;
  const int t = threadIdx.x;
#pragma unroll
  for (int i = 0; i < 4; i++) {
    int idx = t + 256 * i;
    int r = idx >> 4, c4 = idx & 15;
    float4 v = *reinterpret_cast<const float4*>(W + (size_t)(k0 + r) * N + n0 + c4 * 4);
    Ws[r][c4 * 4 + 0] = v.x; Ws[r][c4 * 4 + 1] = v.y;
    Ws[r][c4 * 4 + 2] = v.z; Ws[r][c4 * 4 + 3] = v.w;
  }
  __syncthreads();
#pragma unroll
  for (int i = 0; i < 2; i++) {
    int idx = t + 256 * i;
    int r = idx >> 3, ck = idx & 7;
    half8 h;
#pragma unroll
    for (int j = 0; j < 8; j++) h[j] = (_Float16)Ws[ck * 8 + j][r];
    *reinterpret_cast<half8*>(WT + (size_t)(n0 + r) * K + k0 + ck * 8) = h;
  }
}

// ---------------------------------------------------------------------------
// 256x192 fp16 MFMA GEMM, double-buffered, fine-interleaved staging.
// R13: pointer-increment staging (per-thread global src pointers advance by
// +128 B/tile; no per-tile 64-bit address recompute).
// ---------------------------------------------------------------------------
__global__ __launch_bounds__(512, 2) void gemm256_mfma(
    const _Float16* __restrict__ A, const _Float16* __restrict__ BT,
    const float* __restrict__ bias, _Float16* __restrict__ Cout,
    int M, int N, int K, float scale_lo, int ncut) {
  extern __shared__ char smem[];   // 114688 B: As[2][32K] | Bs[2][24K]
  const int tid = threadIdx.x, w = tid >> 6, lane = tid & 63;
  const int wm = w >> 2, wn = w & 3;

  const int nwg = gridDim.x, cpx = nwg >> 3;
  const int wg = (blockIdx.x & 7) * cpx + (blockIdx.x >> 3);
  const int nbx = N / 192;
  const int bx = wg % nbx, by = wg / nbx;
  const int m0 = by * 256, n0 = bx * 192;

  const int NT = K >> 6;

  // per-thread staging pointers (r = tid>>3 + 64*i; cs invariant in i and kt)
  const int rS = tid >> 3, cS = (tid & 7) ^ (rS & 7);
  const char* Apn = (const char*)(A + (size_t)(m0 + rS) * K + cS * 8);
  const char* Bpn = (const char*)(BT + (size_t)(n0 + rS) * K + cS * 8);
  const size_t strideI = (size_t)64 * K * 2;   // 64 rows per load-slice

  auto stageA1 = [&](int buf, int i) {
    gload16(Apn + i * strideI, smem + buf * 32768 + tid * 16 + i * 8192);
  };
  auto stageB1 = [&](int buf, int i) {
    gload16(Bpn + i * strideI, smem + 65536 + buf * 24576 + tid * 16 + i * 8192);
  };

  floatx4 acc[8][3] = {};

  // prologue: tile 0
#pragma unroll
  for (int i = 0; i < 4; i++) stageA1(0, i);
#pragma unroll
  for (int i = 0; i < 3; i++) stageB1(0, i);
  Apn += 128; Bpn += 128;   // point at tile 1

  for (int kt = 0; kt < NT; ++kt) {
    const int p = kt & 1;
    asm volatile("s_waitcnt vmcnt(0)" ::: "memory");  // tile kt landed
    __builtin_amdgcn_s_barrier();
    __builtin_amdgcn_sched_barrier(0);   // no ds_read hoist above the barrier

    const char* Ab = smem + p * 32768;
    const char* Bb = smem + 65536 + p * 24576;
    const bool more = (kt + 1 < NT);
#pragma unroll
    for (int q = 0; q < 4; q++) {
      half8 af[2][2], bf[3][2];
#pragma unroll
      for (int e = 0; e < 2; e++)
#pragma unroll
        for (int ks = 0; ks < 2; ks++) {
          int row = wm * 128 + (2 * q + e) * 16 + (lane & 15);
          int ch = (ks * 4 + (lane >> 4)) ^ (row & 7);
          af[e][ks] = *reinterpret_cast<const half8*>(Ab + row * 128 + ch * 16);
        }
#pragma unroll
      for (int n = 0; n < 3; n++)
#pragma unroll
        for (int ks = 0; ks < 2; ks++) {
          int row = wn * 48 + n * 16 + (lane & 15);
          int ch = (ks * 4 + (lane >> 4)) ^ (row & 7);
          bf[n][ks] = *reinterpret_cast<const half8*>(Bb + row * 128 + ch * 16);
        }
      if (more) {
        if (q == 0)      { stageA1(p ^ 1, 0); stageA1(p ^ 1, 1); }
        else if (q == 1) { stageA1(p ^ 1, 2); stageA1(p ^ 1, 3); }
        else if (q == 2) { stageB1(p ^ 1, 0); stageB1(p ^ 1, 1); }
        else             { stageB1(p ^ 1, 2); }
      }
      __builtin_amdgcn_s_setprio(1);
#pragma unroll
      for (int ks = 0; ks < 2; ks++)
#pragma unroll
        for (int e = 0; e < 2; e++)
#pragma unroll
          for (int n = 0; n < 3; n++)
            acc[2 * q + e][n] = __builtin_amdgcn_mfma_f32_16x16x32_f16(
                af[e][ks], bf[n][ks], acc[2 * q + e][n], 0, 0, 0);
      __builtin_amdgcn_s_setprio(0);
    }
    Apn += 128; Bpn += 128;
    __builtin_amdgcn_sched_barrier(0);   // no ds_read sink below the barrier
    __builtin_amdgcn_s_barrier();        // buffer p reads done before overwrite
  }

#pragma unroll
  for (int mf = 0; mf < 8; mf++)
#pragma unroll
    for (int n = 0; n < 3; n++) {
      int col = n0 + wn * 48 + n * 16 + (lane & 15);
      float bv = bias[col];
      float sc = (col < ncut) ? scale_lo : 1.0f;
#pragma unroll
      for (int reg = 0; reg < 4; reg++) {
        int row = m0 + wm * 128 + mf * 16 + (lane >> 4) * 4 + reg;
        Cout[(size_t)row * N + col] = (_Float16)((acc[mf][n][reg] + bv) * sc);
      }
    }
}

// ---------------------------------------------------------------------------
// 128x128 fp16 MFMA GEMM (output projection), fine-interleaved, fp32 out.
// R13: pointer-increment staging.
// ---------------------------------------------------------------------------
__global__ __launch_bounds__(256, 2) void gemm128_mfma(
    const _Float16* __restrict__ A, const _Float16* __restrict__ BT,
    const float* __restrict__ bias, float* __restrict__ Cout,
    int M, int N, int K) {
  extern __shared__ char smem[];   // 65536 B: As[2][16K] | Bs[2][16K]
  const int tid = threadIdx.x, w = tid >> 6, lane = tid & 63;
  const int wm = w >> 1, wn = w & 1;

  const int nwg = gridDim.x, cpx = nwg >> 3;
  const int wg = (blockIdx.x & 7) * cpx + (blockIdx.x >> 3);
  const int nbx = N >> 7;
  const int bx = wg % nbx, by = wg / nbx;
  const int m0 = by * 128, n0 = bx * 128;

  const int NT = K >> 6;

  const int rS = tid >> 3, cS = (tid & 7) ^ (rS & 7);
  const char* Apn = (const char*)(A + (size_t)(m0 + rS) * K + cS * 8);
  const char* Bpn = (const char*)(BT + (size_t)(n0 + rS) * K + cS * 8);
  const size_t strideI = (size_t)32 * K * 2;   // 32 rows per load-slice

  auto stageA1 = [&](int buf, int i) {
    gload16(Apn + i * strideI, smem + buf * 16384 + tid * 16 + i * 4096);
  };
  auto stageB1 = [&](int buf, int i) {
    gload16(Bpn + i * strideI, smem + 32768 + buf * 16384 + tid * 16 + i * 4096);
  };

  floatx4 acc[4][4] = {};

#pragma unroll
  for (int i = 0; i < 4; i++) stageA1(0, i);
#pragma unroll
  for (int i = 0; i < 4; i++) stageB1(0, i);
  Apn += 128; Bpn += 128;

  for (int kt = 0; kt < NT; ++kt) {
    const int p = kt & 1;
    asm volatile("s_waitcnt vmcnt(0)" ::: "memory");
    __builtin_amdgcn_s_barrier();
    __builtin_amdgcn_sched_barrier(0);

    const char* Ab = smem + p * 16384;
    const char* Bb = smem + 32768 + p * 16384;
    const bool more = (kt + 1 < NT);

    half8 bf[4][2];
#pragma unroll
    for (int n = 0; n < 4; n++)
#pragma unroll
      for (int ks = 0; ks < 2; ks++) {
        int row = wn * 64 + n * 16 + (lane & 15);
        int ch = (ks * 4 + (lane >> 4)) ^ (row & 7);
        bf[n][ks] = *reinterpret_cast<const half8*>(Bb + row * 128 + ch * 16);
      }

#pragma unroll
    for (int q = 0; q < 4; q++) {
      half8 af[2];
#pragma unroll
      for (int ks = 0; ks < 2; ks++) {
        int row = wm * 64 + q * 16 + (lane & 15);
        int ch = (ks * 4 + (lane >> 4)) ^ (row & 7);
        af[ks] = *reinterpret_cast<const half8*>(Ab + row * 128 + ch * 16);
      }
      if (more) {
        if (q == 0)      { stageA1(p ^ 1, 0); stageA1(p ^ 1, 1); }
        else if (q == 1) { stageA1(p ^ 1, 2); stageA1(p ^ 1, 3); }
        else if (q == 2) { stageB1(p ^ 1, 0); stageB1(p ^ 1, 1); }
        else             { stageB1(p ^ 1, 2); stageB1(p ^ 1, 3); }
      }
      __builtin_amdgcn_s_setprio(1);
#pragma unroll
      for (int ks = 0; ks < 2; ks++)
#pragma unroll
        for (int n = 0; n < 4; n++)
          acc[q][n] = __builtin_amdgcn_mfma_f32_16x16x32_f16(
              af[ks], bf[n][ks], acc[q][n], 0, 0, 0);
      __builtin_amdgcn_s_setprio(0);
    }
    Apn += 128; Bpn += 128;
    __builtin_amdgcn_sched_barrier(0);
    __builtin_amdgcn_s_barrier();
  }

#pragma unroll
  for (int q = 0; q < 4; q++)
#pragma unroll
    for (int n = 0; n < 4; n++) {
      int col = n0 + wn * 64 + n * 16 + (lane & 15);
      float bv = bias[col];
#pragma unroll
      for (int reg = 0; reg < 4; reg++) {
        int row = m0 + wm * 64 + q * 16 + (lane >> 4) * 4 + reg;
        Cout[(size_t)row * N + col] = acc[q][n][reg] + bv;
      }
    }
}

// ---------------------------------------------------------------------------
// V transpose: qkv[B*S][3D] fp16 (V slice) -> Vt[(b*H+h)*64 + d][S] fp16
// ---------------------------------------------------------------------------
__global__ __launch_bounds__(256) void v_transpose(const _Float16* __restrict__ qkv,
                                                   _Float16* __restrict__ Vt) {
  __shared__ _Float16 Vs[64][72];
  const int s0 = blockIdx.x * 64, bh = blockIdx.y;
  const int b = bh >> 4, h = bh & 15;
  const int t = threadIdx.x;
#pragma unroll
  for (int i = 0; i < 2; i++) {
    int idx = t + 256 * i;
    int r = idx >> 3, c = idx & 7;
    half8 v = *reinterpret_cast<const half8*>(
        qkv + (size_t)(b * S_ + s0 + r) * (3 * D_) + 2 * D_ + h * 64 + c * 8);
    *reinterpret_cast<half8*>(&Vs[r][c * 8]) = v;
  }
  __syncthreads();
#pragma unroll
  for (int i = 0; i < 2; i++) {
    int idx = t + 256 * i;
    int d = idx >> 3, c = idx & 7;
    half8 o;
#pragma unroll
    for (int j = 0; j < 8; j++) o[j] = Vs[c * 8 + j][d];
    *reinterpret_cast<half8*>(Vt + ((size_t)bh * 64 + d) * S_ + s0 + c * 8) = o;
  }
}

// ---------------------------------------------------------------------------
// Flash attention — R12 race-proven structure; R13: pointer-increment staging
// (K src +393216 B/tile, V src +128 B/tile; no wrap re-stage — last iter
// drains with vmcnt(0)), #pragma unroll 2 on the tile loop (cb compile-time).
// ---------------------------------------------------------------------------
__global__ __launch_bounds__(256, 4) void flash_mfma(const _Float16* __restrict__ qkv,
                                                     const _Float16* __restrict__ Vt,
                                                     _Float16* __restrict__ Opart,
                                                     float* __restrict__ keys) {
  const int qt = blockIdx.x, h = blockIdx.y;
  const int b = blockIdx.z >> 1, sp = blockIdx.z & 1;
  const int t = threadIdx.x, w = t >> 6, lane = t & 63;
  const int lo = lane & 31, hi = lane >> 5;

  __shared__ _Float16 Ks[2][KVB * 64];    // [kk][d] rows 128B, chunk^(r&7)
  __shared__ _Float16 Vts[2][64 * KVB];   // [d][kk] rows 128B, chunk^(r&7)

  const int qrow = qt * 128 + w * 32 + lo;
  const _Float16* qbase = qkv + (size_t)(b * S_ + qrow) * (3 * D_) + h * 64;
  half8 qf[4];
#pragma unroll
  for (int kd = 0; kd < 4; kd++)
    qf[kd] = *reinterpret_cast<const half8*>(qbase + kd * 16 + hi * 8);
  asm volatile("" : "+v"(qf[0]), "+v"(qf[1]), "+v"(qf[2]), "+v"(qf[3]));

  const size_t kbase = (size_t)(b * S_) * (3 * D_) + D_ + h * 64;
  const size_t vbase = (size_t)(b * H_ + h) * 64 * S_;
  const int kvbase = sp * (S_ / 2);

  // per-thread staging pointers (r = t>>3 [+32]; cs invariant across tiles)
  const int rs = t >> 3, cs = (t & 7) ^ (rs & 7);
  const char* kp = (const char*)(qkv + kbase + (size_t)(kvbase + rs) * (3 * D_) + cs * 8);
  const char* vp = (const char*)(Vt + vbase + (size_t)rs * S_ + kvbase + cs * 8);
  constexpr size_t K_ROW32 = (size_t)32 * 3 * D_ * 2;   // +32 rows in qkv
  constexpr size_t V_ROW32 = (size_t)32 * S_ * 2;       // +32 rows in Vt
  constexpr size_t K_TILE  = (size_t)KVB * 3 * D_ * 2;  // per-tile advance
  constexpr size_t V_TILE  = (size_t)KVB * 2;

  auto stage = [&](int buf) {
    char* kd_ = (char*)&Ks[buf][0] + t * 16;
    char* vd_ = (char*)&Vts[buf][0] + t * 16;
    gload16(kp, kd_);
    gload16(kp + K_ROW32, kd_ + 4096);
    gload16(vp, vd_);
    gload16(vp + V_ROW32, vd_ + 4096);
  };

  floatx16 o0, o1;
#pragma unroll
  for (int r = 0; r < 16; r++) { o0[r] = 0.f; o1[r] = 0.f; }
  float m = -1e30f, l = 0.f;

  stage(0);
  kp += K_TILE; vp += V_TILE;

#pragma unroll 2
  for (int tt = 0; tt < HT; ++tt) {
    const int cb = tt & 1;
    if (tt + 1 < HT) {
      stage(cb ^ 1);
      kp += K_TILE; vp += V_TILE;
      asm volatile("s_waitcnt vmcnt(4)" ::: "memory");  // tile tt landed; next in flight
    } else {
      asm volatile("s_waitcnt vmcnt(0)" ::: "memory");  // last tile: drain
    }
    __builtin_amdgcn_s_barrier();
    __builtin_amdgcn_sched_barrier(0);   // no ds_read hoist above the barrier

    // ---- S^T = K @ Q^T : lane holds q=lo
    const char* kb2 = (const char*)&Ks[cb][0];
    floatx16 s0v, s1v;
#pragma unroll
    for (int r = 0; r < 16; r++) { s0v[r] = 0.f; s1v[r] = 0.f; }
    __builtin_amdgcn_s_setprio(1);
#pragma unroll
    for (int kd = 0; kd < 4; kd++) {
      int r0 = lo, r1 = 32 + lo;
      half8 k0f = *reinterpret_cast<const half8*>(
          kb2 + r0 * 128 + (((kd * 2 + hi) ^ (r0 & 7)) * 16));
      half8 k1f = *reinterpret_cast<const half8*>(
          kb2 + r1 * 128 + (((kd * 2 + hi) ^ (r1 & 7)) * 16));
      s0v = __builtin_amdgcn_mfma_f32_32x32x16_f16(k0f, qf[kd], s0v, 0, 0, 0);
      s1v = __builtin_amdgcn_mfma_f32_32x32x16_f16(k1f, qf[kd], s1v, 0, 0, 0);
    }
    __builtin_amdgcn_s_setprio(0);

    // ---- online softmax (exp2 domain), defer-max THR=8; max3 tree
    float tm[16];
#pragma unroll
    for (int r = 0; r < 16; r++) tm[r] = fmaxf(s0v[r], s1v[r]);
    float u0 = fmaxf(fmaxf(tm[0], tm[1]), tm[2]);
    float u1 = fmaxf(fmaxf(tm[3], tm[4]), tm[5]);
    float u2 = fmaxf(fmaxf(tm[6], tm[7]), tm[8]);
    float u3 = fmaxf(fmaxf(tm[9], tm[10]), tm[11]);
    float u4 = fmaxf(fmaxf(tm[12], tm[13]), tm[14]);
    float pm = fmaxf(fmaxf(u0, u1), u2);
    pm = fmaxf(fmaxf(pm, u3), u4);
    pm = fmaxf(pm, tm[15]);
    pm = fmaxf(pm, __shfl_xor(pm, 32));
    if (!__all(pm <= m + 8.0f)) {
      float mn = fmaxf(m, pm);
      float al = __builtin_amdgcn_exp2f(m - mn);
      m = mn; l *= al;
#pragma unroll
      for (int r = 0; r < 16; r++) { o0[r] *= al; o1[r] *= al; }
    }
    float rr[16];
#pragma unroll
    for (int r = 0; r < 16; r++) {
      s0v[r] = __builtin_amdgcn_exp2f(s0v[r] - m);
      s1v[r] = __builtin_amdgcn_exp2f(s1v[r] - m);
      rr[r] = s0v[r] + s1v[r];
    }
#pragma unroll
    for (int st = 8; st >= 1; st >>= 1)
#pragma unroll
      for (int r = 0; r < st; r++) rr[r] += rr[r + st];
    float rs2 = rr[0];
    rs2 += __shfl_xor(rs2, 32);
    l += rs2;

    // ---- convert P to fp16 B-fragments (cvt_pk + permlane)
    half8 pf0a, pf0b, pf1a, pf1b;
    {
      unsigned a0 = __builtin_bit_cast(unsigned, __builtin_amdgcn_cvt_pkrtz(s0v[0], s0v[1]));
      unsigned b0 = __builtin_bit_cast(unsigned, __builtin_amdgcn_cvt_pkrtz(s0v[4], s0v[5]));
      unsigned a1 = __builtin_bit_cast(unsigned, __builtin_amdgcn_cvt_pkrtz(s0v[2], s0v[3]));
      unsigned b1 = __builtin_bit_cast(unsigned, __builtin_amdgcn_cvt_pkrtz(s0v[6], s0v[7]));
      asm("v_permlane32_swap_b32 %0, %1" : "+v"(a0), "+v"(b0));
      asm("v_permlane32_swap_b32 %0, %1" : "+v"(a1), "+v"(b1));
      uint4v u; u[0] = a0; u[1] = a1; u[2] = b0; u[3] = b1;
      pf0a = __builtin_bit_cast(half8, u);
      a0 = __builtin_bit_cast(unsigned, __builtin_amdgcn_cvt_pkrtz(s0v[8], s0v[9]));
      b0 = __builtin_bit_cast(unsigned, __builtin_amdgcn_cvt_pkrtz(s0v[12], s0v[13]));
      a1 = __builtin_bit_cast(unsigned, __builtin_amdgcn_cvt_pkrtz(s0v[10], s0v[11]));
      b1 = __builtin_bit_cast(unsigned, __builtin_amdgcn_cvt_pkrtz(s0v[14], s0v[15]));
      asm("v_permlane32_swap_b32 %0, %1" : "+v"(a0), "+v"(b0));
      asm("v_permlane32_swap_b32 %0, %1" : "+v"(a1), "+v"(b1));
      u[0] = a0; u[1] = a1; u[2] = b0; u[3] = b1;
      pf0b = __builtin_bit_cast(half8, u);
      a0 = __builtin_bit_cast(unsigned, __builtin_amdgcn_cvt_pkrtz(s1v[0], s1v[1]));
      b0 = __builtin_bit_cast(unsigned, __builtin_amdgcn_cvt_pkrtz(s1v[4], s1v[5]));
      a1 = __builtin_bit_cast(unsigned, __builtin_amdgcn_cvt_pkrtz(s1v[2], s1v[3]));
      b1 = __builtin_bit_cast(unsigned, __builtin_amdgcn_cvt_pkrtz(s1v[6], s1v[7]));
      asm("v_permlane32_swap_b32 %0, %1" : "+v"(a0), "+v"(b0));
      asm("v_permlane32_swap_b32 %0, %1" : "+v"(a1), "+v"(b1));
      u[0] = a0; u[1] = a1; u[2] = b0; u[3] = b1;
      pf1a = __builtin_bit_cast(half8, u);
      a0 = __builtin_bit_cast(unsigned, __builtin_amdgcn_cvt_pkrtz(s1v[8], s1v[9]));
      b0 = __builtin_bit_cast(unsigned, __builtin_amdgcn_cvt_pkrtz(s1v[12], s1v[13]));
      a1 = __builtin_bit_cast(unsigned, __builtin_amdgcn_cvt_pkrtz(s1v[10], s1v[11]));
      b1 = __builtin_bit_cast(unsigned, __builtin_amdgcn_cvt_pkrtz(s1v[14], s1v[15]));
      asm("v_permlane32_swap_b32 %0, %1" : "+v"(a0), "+v"(b0));
      asm("v_permlane32_swap_b32 %0, %1" : "+v"(a1), "+v"(b1));
      u[0] = a0; u[1] = a1; u[2] = b0; u[3] = b1;
      pf1b = __builtin_bit_cast(half8, u);
    }

    // ---- O^T += V^T @ P^T ; V from LDS
    const char* vb2 = (const char*)&Vts[cb][0];
    __builtin_amdgcn_s_setprio(1);
#pragma unroll
    for (int ks = 0; ks < 4; ks++) {
      half8 pf = (ks == 0) ? pf0a : (ks == 1) ? pf0b : (ks == 2) ? pf1a : pf1b;
      const int ch = ks * 2 + hi;
      half8 vf0 = *reinterpret_cast<const half8*>(vb2 + lo * 128 + ((ch ^ (lo & 7)) * 16));
      half8 vf1 = *reinterpret_cast<const half8*>(vb2 + (lo + 32) * 128 + ((ch ^ (lo & 7)) * 16));
      o0 = __builtin_amdgcn_mfma_f32_32x32x16_f16(vf0, pf, o0, 0, 0, 0);
      o1 = __builtin_amdgcn_mfma_f32_32x32x16_f16(vf1, pf, o1, 0, 0, 0);
    }
    __builtin_amdgcn_s_setprio(0);

    __builtin_amdgcn_sched_barrier(0);   // no ds_read sink below the barrier
    __builtin_amdgcn_s_barrier();
  }

  float inv = 1.0f / l;
  const int gr = (b * H_ + h) * S_ + qrow;
  _Float16* ob = Opart + ((size_t)sp * NR_ + gr) * 64;
#pragma unroll
  for (int mt = 0; mt < 2; mt++)
#pragma unroll
    for (int rq = 0; rq < 4; rq++) {
      half4 v;
#pragma unroll
      for (int e = 0; e < 4; e++) v[e] = (_Float16)(((mt ? o1 : o0)[4 * rq + e]) * inv);
      *reinterpret_cast<half4*>(ob + 32 * mt + 8 * rq + 4 * hi) = v;
    }
  if (hi == 0) keys[sp * NR_ + gr] = m + __log2f(l);
}

// ---------------------------------------------------------------------------
// Combine the two KV-split halves: out = (w0*O0 + w1*O1)/(w0+w1), wi = 2^keyi
// ---------------------------------------------------------------------------
__global__ __launch_bounds__(256) void flash_combine(const _Float16* __restrict__ Opart,
                                                     const float* __restrict__ keys,
                                                     _Float16* __restrict__ attn_out) {
  const int gr = blockIdx.x * 256 + threadIdx.x;
  const float k0 = keys[gr], k1 = keys[NR_ + gr];
  const float mx = fmaxf(k0, k1);
  const float w0 = __builtin_amdgcn_exp2f(k0 - mx);
  const float w1 = __builtin_amdgcn_exp2f(k1 - mx);
  const float inv = 1.0f / (w0 + w1);
  const float a0 = w0 * inv, a1 = w1 * inv;
  const int bh = gr >> 11, qs = gr & 2047, b = bh >> 4, h = bh & 15;
  const half8* p0 = reinterpret_cast<const half8*>(Opart + (size_t)gr * 64);
  const half8* p1 = reinterpret_cast<const half8*>(Opart + ((size_t)NR_ + gr) * 64);
  half8* ob = reinterpret_cast<half8*>(
      attn_out + ((size_t)(b * S_ + qs)) * D_ + h * 64);
#pragma unroll
  for (int j = 0; j < 8; j++) {
    half8 x0 = p0[j], x1 = p1[j];
    half8 o;
#pragma unroll
    for (int e = 0; e < 8; e++)
      o[e] = (_Float16)(a0 * (float)x0[e] + a1 * (float)x1[e]);
    ob[j] = o;
  }
}

// ---------------------------------------------------------------------------
extern "C" void kernel_launch(void* const* d_in, const int* in_sizes, int n_in,
                              void* d_out, int out_size, void* d_ws, size_t ws_size,
                              hipStream_t stream) {
  const float* x     = (const float*)d_in[0];
  const float* W_qkv = (const float*)d_in[1];
  const float* b_qkv = (const float*)d_in[2];
  const float* W_out = (const float*)d_in[3];
  const float* b_out = (const float*)d_in[4];
  float* out = (float*)d_out;

  _Float16* xh    = (_Float16*)d_ws;
  _Float16* qkvh  = xh + (size_t)M_ * D_;
  _Float16* Vth   = qkvh + (size_t)M_ * 3 * D_;
  _Float16* WoT   = Vth + (size_t)B_ * H_ * 64 * S_;
  _Float16* WqT   = WoT + (size_t)D_ * D_;
  _Float16* Opart = WqT;                                  // alias (WqT dead by flash)
  float*    keys  = (float*)(Opart + (size_t)2 * NR_ * 64);
  _Float16* atth  = xh;                                   // alias (xh dead by combine)

  cast_f32_f16<<<(M_ * D_ / 8 + 255) / 256, 256, 0, stream>>>(x, xh, M_ * D_ / 8);
  transpose_cast2<<<dim3(3 * D_ / 64, D_ / 64, 2), 256, 0, stream>>>(
      W_qkv, WqT, W_out, WoT);

  gemm256_mfma<<<256, 512, 114688, stream>>>(
      xh, WqT, b_qkv, qkvh, M_, 3 * D_, D_, QSCALE, D_);

  v_transpose<<<dim3(S_ / 64, B_ * H_), 256, 0, stream>>>(qkvh, Vth);

  flash_mfma<<<dim3(S_ / 128, H_, B_ * 2), 256, 0, stream>>>(qkvh, Vth, Opart, keys);

  flash_combine<<<NR_ / 256, 256, 0, stream>>>(Opart, keys, atth);

  gemm128_mfma<<<256, 256, 65536, stream>>>(
      atth, WoT, b_out, out, M_, D_, D_);
}

// Round 14
// 126.193 us; speedup vs baseline: 1.3360x; 1.0022x over previous
//
#include <hip/hip_runtime.h>

typedef _Float16 half8  __attribute__((ext_vector_type(8)));
typedef _Float16 half4  __attribute__((ext_vector_type(4)));
typedef float    floatx4  __attribute__((ext_vector_type(4)));
typedef float    floatx16 __attribute__((ext_vector_type(16)));
typedef unsigned int uint4v __attribute__((ext_vector_type(4)));

constexpr int B_ = 2, S_ = 2048, D_ = 1024, H_ = 16, M_ = 4096;
constexpr int NR_ = B_ * H_ * S_;               // 65536 (b,h,s) rows
constexpr float QSCALE = 0.18033688011112042f;  // log2(e)/8
constexpr int KVB = 64;                         // kv tile
constexpr int HT = 16;                          // tiles per half (1024/64)

__device__ __forceinline__ void gload16(const void* g, void* l) {
  __builtin_amdgcn_global_load_lds((const __attribute__((address_space(1))) void*)g,
                                   (__attribute__((address_space(3))) void*)l, 16, 0, 0);
}

// ---------------------------------------------------------------------------
// cast fp32 -> fp16, 8 elems/thread
// ---------------------------------------------------------------------------
__global__ __launch_bounds__(256) void cast_f32_f16(const float* __restrict__ in,
                                                    _Float16* __restrict__ out, int n8) {
  int i = blockIdx.x * 256 + threadIdx.x;
  if (i >= n8) return;
  float4 a = reinterpret_cast<const float4*>(in)[2 * i];
  float4 b = reinterpret_cast<const float4*>(in)[2 * i + 1];
  half8 h;
  h[0] = (_Float16)a.x; h[1] = (_Float16)a.y; h[2] = (_Float16)a.z; h[3] = (_Float16)a.w;
  h[4] = (_Float16)b.x; h[5] = (_Float16)b.y; h[6] = (_Float16)b.z; h[7] = (_Float16)b.w;
  reinterpret_cast<half8*>(out)[i] = h;
}

// ---------------------------------------------------------------------------
// W[K][N] fp32 -> WT[N][K] fp16 (64x64 tiles). z selects {W_qkv, W_out}.
// ---------------------------------------------------------------------------
__global__ __launch_bounds__(256) void transpose_cast2(const float* __restrict__ W0,
                                                       _Float16* __restrict__ WT0,
                                                       const float* __restrict__ W1,
                                                       _Float16* __restrict__ WT1) {
  __shared__ float Ws[64][65];
  const int z = blockIdx.z;
  const int NW = z ? D_ : 3 * D_;
  if (blockIdx.x * 64 >= NW) return;
  const float* W = z ? W1 : W0;
  _Float16* WT = z ? WT1 : WT0;
  const int K = D_, N = NW;
  const int n0 = blockIdx.x * 64, k0 = blockIdx.y * 64;
  const int t = threadIdx.x;
#pragma unroll
  for (int i = 0; i < 4; i++) {
    int idx = t + 256 * i;
    int r = idx >> 4, c4 = idx & 15;
    float4 v = *reinterpret_cast<const float4*>(W + (size_t)(k0 + r) * N + n0 + c4 * 4);
    Ws[r][c4 * 4 + 0] = v.x; Ws[r][c4 * 4 + 1] = v.y;
    Ws[r][c4 * 4 + 2] = v.z; Ws[r][c4 * 4 + 3] = v.w;
  }
  __syncthreads();
#pragma unroll
  for (int i = 0; i < 2; i++) {
    int idx = t + 256 * i;
    int r = idx >> 3, ck = idx & 7;
    half8 h;
#pragma unroll
    for (int j = 0; j < 8; j++) h[j] = (_Float16)Ws[ck * 8 + j][r];
    *reinterpret_cast<half8*>(WT + (size_t)(n0 + r) * K + k0 + ck * 8) = h;
  }
}

// ---------------------------------------------------------------------------
// 256x192 fp16 MFMA GEMM, double-buffered, fine-interleaved staging.
// R14: wave grid re-tiled 2Mx4N -> 4Mx2N (64x96 per wave) with B fragments
// hoisted once per K-tile: ds_read_b128 per tile per wave 40 -> 20 for the
// same 48 MFMA. Old layout was LDS-read-bound (2560 clk LDS vs 1920 MFMA per
// CU-tile); new is MFMA-bound (1280 vs 1920). Sync skeleton unchanged
// (race-proven R8-R13).
// ---------------------------------------------------------------------------
__global__ __launch_bounds__(512, 2) void gemm256_mfma(
    const _Float16* __restrict__ A, const _Float16* __restrict__ BT,
    const float* __restrict__ bias, _Float16* __restrict__ Cout,
    int M, int N, int K, float scale_lo, int ncut) {
  extern __shared__ char smem[];   // 114688 B: As[2][32K] | Bs[2][24K]
  const int tid = threadIdx.x, w = tid >> 6, lane = tid & 63;
  const int wm = w >> 1, wn = w & 1;   // 4 waves down M, 2 across N

  const int nwg = gridDim.x, cpx = nwg >> 3;
  const int wg = (blockIdx.x & 7) * cpx + (blockIdx.x >> 3);
  const int nbx = N / 192;
  const int bx = wg % nbx, by = wg / nbx;
  const int m0 = by * 256, n0 = bx * 192;

  const int NT = K >> 6;

  // per-thread staging pointers (r = tid>>3 + 64*i; cs invariant in i and kt)
  const int rS = tid >> 3, cS = (tid & 7) ^ (rS & 7);
  const char* Apn = (const char*)(A + (size_t)(m0 + rS) * K + cS * 8);
  const char* Bpn = (const char*)(BT + (size_t)(n0 + rS) * K + cS * 8);
  const size_t strideI = (size_t)64 * K * 2;   // 64 rows per load-slice

  auto stageA1 = [&](int buf, int i) {
    gload16(Apn + i * strideI, smem + buf * 32768 + tid * 16 + i * 8192);
  };
  auto stageB1 = [&](int buf, int i) {
    gload16(Bpn + i * strideI, smem + 65536 + buf * 24576 + tid * 16 + i * 8192);
  };

  floatx4 acc[4][6] = {};

  // prologue: tile 0
#pragma unroll
  for (int i = 0; i < 4; i++) stageA1(0, i);
#pragma unroll
  for (int i = 0; i < 3; i++) stageB1(0, i);
  Apn += 128; Bpn += 128;   // point at tile 1

  for (int kt = 0; kt < NT; ++kt) {
    const int p = kt & 1;
    asm volatile("s_waitcnt vmcnt(0)" ::: "memory");  // tile kt landed
    __builtin_amdgcn_s_barrier();
    __builtin_amdgcn_sched_barrier(0);   // no ds_read hoist above the barrier

    const char* Ab = smem + p * 32768;
    const char* Bb = smem + 65536 + p * 24576;
    const bool more = (kt + 1 < NT);

    // hoist all B fragments once per K-tile (reused by all 4 M frags)
    half8 bf[6][2];
#pragma unroll
    for (int n = 0; n < 6; n++)
#pragma unroll
      for (int ks = 0; ks < 2; ks++) {
        int row = wn * 96 + n * 16 + (lane & 15);
        int ch = (ks * 4 + (lane >> 4)) ^ (row & 7);
        bf[n][ks] = *reinterpret_cast<const half8*>(Bb + row * 128 + ch * 16);
      }

#pragma unroll
    for (int q = 0; q < 4; q++) {
      half8 af[2];
#pragma unroll
      for (int ks = 0; ks < 2; ks++) {
        int row = wm * 64 + q * 16 + (lane & 15);
        int ch = (ks * 4 + (lane >> 4)) ^ (row & 7);
        af[ks] = *reinterpret_cast<const half8*>(Ab + row * 128 + ch * 16);
      }
      if (more) {
        if (q == 0)      { stageA1(p ^ 1, 0); stageA1(p ^ 1, 1); }
        else if (q == 1) { stageA1(p ^ 1, 2); stageA1(p ^ 1, 3); }
        else if (q == 2) { stageB1(p ^ 1, 0); stageB1(p ^ 1, 1); }
        else             { stageB1(p ^ 1, 2); }
      }
      __builtin_amdgcn_s_setprio(1);
#pragma unroll
      for (int ks = 0; ks < 2; ks++)
#pragma unroll
        for (int n = 0; n < 6; n++)
          acc[q][n] = __builtin_amdgcn_mfma_f32_16x16x32_f16(
              af[ks], bf[n][ks], acc[q][n], 0, 0, 0);
      __builtin_amdgcn_s_setprio(0);
    }
    Apn += 128; Bpn += 128;
    __builtin_amdgcn_sched_barrier(0);   // no ds_read sink below the barrier
    __builtin_amdgcn_s_barrier();        // buffer p reads done before overwrite
  }

#pragma unroll
  for (int mf = 0; mf < 4; mf++)
#pragma unroll
    for (int n = 0; n < 6; n++) {
      int col = n0 + wn * 96 + n * 16 + (lane & 15);
      float bv = bias[col];
      float sc = (col < ncut) ? scale_lo : 1.0f;
#pragma unroll
      for (int reg = 0; reg < 4; reg++) {
        int row = m0 + wm * 64 + mf * 16 + (lane >> 4) * 4 + reg;
        Cout[(size_t)row * N + col] = (_Float16)((acc[mf][n][reg] + bv) * sc);
      }
    }
}

// ---------------------------------------------------------------------------
// 128x128 fp16 MFMA GEMM (output projection), fine-interleaved, fp32 out.
// (16 ds_read per 32 MFMA -> already MFMA-bound; unchanged from R13)
// ---------------------------------------------------------------------------
__global__ __launch_bounds__(256, 2) void gemm128_mfma(
    const _Float16* __restrict__ A, const _Float16* __restrict__ BT,
    const float* __restrict__ bias, float* __restrict__ Cout,
    int M, int N, int K) {
  extern __shared__ char smem[];   // 65536 B: As[2][16K] | Bs[2][16K]
  const int tid = threadIdx.x, w = tid >> 6, lane = tid & 63;
  const int wm = w >> 1, wn = w & 1;

  const int nwg = gridDim.x, cpx = nwg >> 3;
  const int wg = (blockIdx.x & 7) * cpx + (blockIdx.x >> 3);
  const int nbx = N >> 7;
  const int bx = wg % nbx, by = wg / nbx;
  const int m0 = by * 128, n0 = bx * 128;

  const int NT = K >> 6;

  const int rS = tid >> 3, cS = (tid & 7) ^ (rS & 7);
  const char* Apn = (const char*)(A + (size_t)(m0 + rS) * K + cS * 8);
  const char* Bpn = (const char*)(BT + (size_t)(n0 + rS) * K + cS * 8);
  const size_t strideI = (size_t)32 * K * 2;   // 32 rows per load-slice

  auto stageA1 = [&](int buf, int i) {
    gload16(Apn + i * strideI, smem + buf * 16384 + tid * 16 + i * 4096);
  };
  auto stageB1 = [&](int buf, int i) {
    gload16(Bpn + i * strideI, smem + 32768 + buf * 16384 + tid * 16 + i * 4096);
  };

  floatx4 acc[4][4] = {};

#pragma unroll
  for (int i = 0; i < 4; i++) stageA1(0, i);
#pragma unroll
  for (int i = 0; i < 4; i++) stageB1(0, i);
  Apn += 128; Bpn += 128;

  for (int kt = 0; kt < NT; ++kt) {
    const int p = kt & 1;
    asm volatile("s_waitcnt vmcnt(0)" ::: "memory");
    __builtin_amdgcn_s_barrier();
    __builtin_amdgcn_sched_barrier(0);

    const char* Ab = smem + p * 16384;
    const char* Bb = smem + 32768 + p * 16384;
    const bool more = (kt + 1 < NT);

    half8 bf[4][2];
#pragma unroll
    for (int n = 0; n < 4; n++)
#pragma unroll
      for (int ks = 0; ks < 2; ks++) {
        int row = wn * 64 + n * 16 + (lane & 15);
        int ch = (ks * 4 + (lane >> 4)) ^ (row & 7);
        bf[n][ks] = *reinterpret_cast<const half8*>(Bb + row * 128 + ch * 16);
      }

#pragma unroll
    for (int q = 0; q < 4; q++) {
      half8 af[2];
#pragma unroll
      for (int ks = 0; ks < 2; ks++) {
        int row = wm * 64 + q * 16 + (lane & 15);
        int ch = (ks * 4 + (lane >> 4)) ^ (row & 7);
        af[ks] = *reinterpret_cast<const half8*>(Ab + row * 128 + ch * 16);
      }
      if (more) {
        if (q == 0)      { stageA1(p ^ 1, 0); stageA1(p ^ 1, 1); }
        else if (q == 1) { stageA1(p ^ 1, 2); stageA1(p ^ 1, 3); }
        else if (q == 2) { stageB1(p ^ 1, 0); stageB1(p ^ 1, 1); }
        else             { stageB1(p ^ 1, 2); stageB1(p ^ 1, 3); }
      }
      __builtin_amdgcn_s_setprio(1);
#pragma unroll
      for (int ks = 0; ks < 2; ks++)
#pragma unroll
        for (int n = 0; n < 4; n++)
          acc[q][n] = __builtin_amdgcn_mfma_f32_16x16x32_f16(
              af[ks], bf[n][ks], acc[q][n], 0, 0, 0);
      __builtin_amdgcn_s_setprio(0);
    }
    Apn += 128; Bpn += 128;
    __builtin_amdgcn_sched_barrier(0);
    __builtin_amdgcn_s_barrier();
  }

#pragma unroll
  for (int q = 0; q < 4; q++)
#pragma unroll
    for (int n = 0; n < 4; n++) {
      int col = n0 + wn * 64 + n * 16 + (lane & 15);
      float bv = bias[col];
#pragma unroll
      for (int reg = 0; reg < 4; reg++) {
        int row = m0 + wm * 64 + q * 16 + (lane >> 4) * 4 + reg;
        Cout[(size_t)row * N + col] = acc[q][n][reg] + bv;
      }
    }
}

// ---------------------------------------------------------------------------
// V transpose: qkv[B*S][3D] fp16 (V slice) -> Vt[(b*H+h)*64 + d][S] fp16
// ---------------------------------------------------------------------------
__global__ __launch_bounds__(256) void v_transpose(const _Float16* __restrict__ qkv,
                                                   _Float16* __restrict__ Vt) {
  __shared__ _Float16 Vs[64][72];
  const int s0 = blockIdx.x * 64, bh = blockIdx.y;
  const int b = bh >> 4, h = bh & 15;
  const int t = threadIdx.x;
#pragma unroll
  for (int i = 0; i < 2; i++) {
    int idx = t + 256 * i;
    int r = idx >> 3, c = idx & 7;
    half8 v = *reinterpret_cast<const half8*>(
        qkv + (size_t)(b * S_ + s0 + r) * (3 * D_) + 2 * D_ + h * 64 + c * 8);
    *reinterpret_cast<half8*>(&Vs[r][c * 8]) = v;
  }
  __syncthreads();
#pragma unroll
  for (int i = 0; i < 2; i++) {
    int idx = t + 256 * i;
    int d = idx >> 3, c = idx & 7;
    half8 o;
#pragma unroll
    for (int j = 0; j < 8; j++) o[j] = Vs[c * 8 + j][d];
    *reinterpret_cast<half8*>(Vt + ((size_t)bh * 64 + d) * S_ + s0 + c * 8) = o;
  }
}

// ---------------------------------------------------------------------------
// Flash attention — R13 structure unchanged (near known-achievable for D=64).
// ---------------------------------------------------------------------------
__global__ __launch_bounds__(256, 4) void flash_mfma(const _Float16* __restrict__ qkv,
                                                     const _Float16* __restrict__ Vt,
                                                     _Float16* __restrict__ Opart,
                                                     float* __restrict__ keys) {
  const int qt = blockIdx.x, h = blockIdx.y;
  const int b = blockIdx.z >> 1, sp = blockIdx.z & 1;
  const int t = threadIdx.x, w = t >> 6, lane = t & 63;
  const int lo = lane & 31, hi = lane >> 5;

  __shared__ _Float16 Ks[2][KVB * 64];    // [kk][d] rows 128B, chunk^(r&7)
  __shared__ _Float16 Vts[2][64 * KVB];   // [d][kk] rows 128B, chunk^(r&7)

  const int qrow = qt * 128 + w * 32 + lo;
  const _Float16* qbase = qkv + (size_t)(b * S_ + qrow) * (3 * D_) + h * 64;
  half8 qf[4];
#pragma unroll
  for (int kd = 0; kd < 4; kd++)
    qf[kd] = *reinterpret_cast<const half8*>(qbase + kd * 16 + hi * 8);
  asm volatile("" : "+v"(qf[0]), "+v"(qf[1]), "+v"(qf[2]), "+v"(qf[3]));

  const size_t kbase = (size_t)(b * S_) * (3 * D_) + D_ + h * 64;
  const size_t vbase = (size_t)(b * H_ + h) * 64 * S_;
  const int kvbase = sp * (S_ / 2);

  const int rs = t >> 3, cs = (t & 7) ^ (rs & 7);
  const char* kp = (const char*)(qkv + kbase + (size_t)(kvbase + rs) * (3 * D_) + cs * 8);
  const char* vp = (const char*)(Vt + vbase + (size_t)rs * S_ + kvbase + cs * 8);
  constexpr size_t K_ROW32 = (size_t)32 * 3 * D_ * 2;   // +32 rows in qkv
  constexpr size_t V_ROW32 = (size_t)32 * S_ * 2;       // +32 rows in Vt
  constexpr size_t K_TILE  = (size_t)KVB * 3 * D_ * 2;  // per-tile advance
  constexpr size_t V_TILE  = (size_t)KVB * 2;

  auto stage = [&](int buf) {
    char* kd_ = (char*)&Ks[buf][0] + t * 16;
    char* vd_ = (char*)&Vts[buf][0] + t * 16;
    gload16(kp, kd_);
    gload16(kp + K_ROW32, kd_ + 4096);
    gload16(vp, vd_);
    gload16(vp + V_ROW32, vd_ + 4096);
  };

  floatx16 o0, o1;
#pragma unroll
  for (int r = 0; r < 16; r++) { o0[r] = 0.f; o1[r] = 0.f; }
  float m = -1e30f, l = 0.f;

  stage(0);
  kp += K_TILE; vp += V_TILE;

#pragma unroll 2
  for (int tt = 0; tt < HT; ++tt) {
    const int cb = tt & 1;
    if (tt + 1 < HT) {
      stage(cb ^ 1);
      kp += K_TILE; vp += V_TILE;
      asm volatile("s_waitcnt vmcnt(4)" ::: "memory");  // tile tt landed; next in flight
    } else {
      asm volatile("s_waitcnt vmcnt(0)" ::: "memory");  // last tile: drain
    }
    __builtin_amdgcn_s_barrier();
    __builtin_amdgcn_sched_barrier(0);   // no ds_read hoist above the barrier

    // ---- S^T = K @ Q^T : lane holds q=lo
    const char* kb2 = (const char*)&Ks[cb][0];
    floatx16 s0v, s1v;
#pragma unroll
    for (int r = 0; r < 16; r++) { s0v[r] = 0.f; s1v[r] = 0.f; }
    __builtin_amdgcn_s_setprio(1);
#pragma unroll
    for (int kd = 0; kd < 4; kd++) {
      int r0 = lo, r1 = 32 + lo;
      half8 k0f = *reinterpret_cast<const half8*>(
          kb2 + r0 * 128 + (((kd * 2 + hi) ^ (r0 & 7)) * 16));
      half8 k1f = *reinterpret_cast<const half8*>(
          kb2 + r1 * 128 + (((kd * 2 + hi) ^ (r1 & 7)) * 16));
      s0v = __builtin_amdgcn_mfma_f32_32x32x16_f16(k0f, qf[kd], s0v, 0, 0, 0);
      s1v = __builtin_amdgcn_mfma_f32_32x32x16_f16(k1f, qf[kd], s1v, 0, 0, 0);
    }
    __builtin_amdgcn_s_setprio(0);

    // ---- online softmax (exp2 domain), defer-max THR=8; max3 tree
    float tm[16];
#pragma unroll
    for (int r = 0; r < 16; r++) tm[r] = fmaxf(s0v[r], s1v[r]);
    float u0 = fmaxf(fmaxf(tm[0], tm[1]), tm[2]);
    float u1 = fmaxf(fmaxf(tm[3], tm[4]), tm[5]);
    float u2 = fmaxf(fmaxf(tm[6], tm[7]), tm[8]);
    float u3 = fmaxf(fmaxf(tm[9], tm[10]), tm[11]);
    float u4 = fmaxf(fmaxf(tm[12], tm[13]), tm[14]);
    float pm = fmaxf(fmaxf(u0, u1), u2);
    pm = fmaxf(fmaxf(pm, u3), u4);
    pm = fmaxf(pm, tm[15]);
    pm = fmaxf(pm, __shfl_xor(pm, 32));
    if (!__all(pm <= m + 8.0f)) {
      float mn = fmaxf(m, pm);
      float al = __builtin_amdgcn_exp2f(m - mn);
      m = mn; l *= al;
#pragma unroll
      for (int r = 0; r < 16; r++) { o0[r] *= al; o1[r] *= al; }
    }
    float rr[16];
#pragma unroll
    for (int r = 0; r < 16; r++) {
      s0v[r] = __builtin_amdgcn_exp2f(s0v[r] - m);
      s1v[r] = __builtin_amdgcn_exp2f(s1v[r] - m);
      rr[r] = s0v[r] + s1v[r];
    }
#pragma unroll
    for (int st = 8; st >= 1; st >>= 1)
#pragma unroll
      for (int r = 0; r < st; r++) rr[r] += rr[r + st];
    float rs2 = rr[0];
    rs2 += __shfl_xor(rs2, 32);
    l += rs2;

    // ---- convert P to fp16 B-fragments (cvt_pk + permlane)
    half8 pf0a, pf0b, pf1a, pf1b;
    {
      unsigned a0 = __builtin_bit_cast(unsigned, __builtin_amdgcn_cvt_pkrtz(s0v[0], s0v[1]));
      unsigned b0 = __builtin_bit_cast(unsigned, __builtin_amdgcn_cvt_pkrtz(s0v[4], s0v[5]));
      unsigned a1 = __builtin_bit_cast(unsigned, __builtin_amdgcn_cvt_pkrtz(s0v[2], s0v[3]));
      unsigned b1 = __builtin_bit_cast(unsigned, __builtin_amdgcn_cvt_pkrtz(s0v[6], s0v[7]));
      asm("v_permlane32_swap_b32 %0, %1" : "+v"(a0), "+v"(b0));
      asm("v_permlane32_swap_b32 %0, %1" : "+v"(a1), "+v"(b1));
      uint4v u; u[0] = a0; u[1] = a1; u[2] = b0; u[3] = b1;
      pf0a = __builtin_bit_cast(half8, u);
      a0 = __builtin_bit_cast(unsigned, __builtin_amdgcn_cvt_pkrtz(s0v[8], s0v[9]));
      b0 = __builtin_bit_cast(unsigned, __builtin_amdgcn_cvt_pkrtz(s0v[12], s0v[13]));
      a1 = __builtin_bit_cast(unsigned, __builtin_amdgcn_cvt_pkrtz(s0v[10], s0v[11]));
      b1 = __builtin_bit_cast(unsigned, __builtin_amdgcn_cvt_pkrtz(s0v[14], s0v[15]));
      asm("v_permlane32_swap_b32 %0, %1" : "+v"(a0), "+v"(b0));
      asm("v_permlane32_swap_b32 %0, %1" : "+v"(a1), "+v"(b1));
      u[0] = a0; u[1] = a1; u[2] = b0; u[3] = b1;
      pf0b = __builtin_bit_cast(half8, u);
      a0 = __builtin_bit_cast(unsigned, __builtin_amdgcn_cvt_pkrtz(s1v[0], s1v[1]));
      b0 = __builtin_bit_cast(unsigned, __builtin_amdgcn_cvt_pkrtz(s1v[4], s1v[5]));
      a1 = __builtin_bit_cast(unsigned, __builtin_amdgcn_cvt_pkrtz(s1v[2], s1v[3]));
      b1 = __builtin_bit_cast(unsigned, __builtin_amdgcn_cvt_pkrtz(s1v[6], s1v[7]));
      asm("v_permlane32_swap_b32 %0, %1" : "+v"(a0), "+v"(b0));
      asm("v_permlane32_swap_b32 %0, %1" : "+v"(a1), "+v"(b1));
      u[0] = a0; u[1] = a1; u[2] = b0; u[3] = b1;
      pf1a = __builtin_bit_cast(half8, u);
      a0 = __builtin_bit_cast(unsigned, __builtin_amdgcn_cvt_pkrtz(s1v[8], s1v[9]));
      b0 = __builtin_bit_cast(unsigned, __builtin_amdgcn_cvt_pkrtz(s1v[12], s1v[13]));
      a1 = __builtin_bit_cast(unsigned, __builtin_amdgcn_cvt_pkrtz(s1v[10], s1v[11]));
      b1 = __builtin_bit_cast(unsigned, __builtin_amdgcn_cvt_pkrtz(s1v[14], s1v[15]));
      asm("v_permlane32_swap_b32 %0, %1" : "+v"(a0), "+v"(b0));
      asm("v_permlane32_swap_b32 %0, %1" : "+v"(a1), "+v"(b1));
      u[0] = a0; u[1] = a1; u[2] = b0; u[3] = b1;
      pf1b = __builtin_bit_cast(half8, u);
    }

    // ---- O^T += V^T @ P^T ; V from LDS
    const char* vb2 = (const char*)&Vts[cb][0];
    __builtin_amdgcn_s_setprio(1);
#pragma unroll
    for (int ks = 0; ks < 4; ks++) {
      half8 pf = (ks == 0) ? pf0a : (ks == 1) ? pf0b : (ks == 2) ? pf1a : pf1b;
      const int ch = ks * 2 + hi;
      half8 vf0 = *reinterpret_cast<const half8*>(vb2 + lo * 128 + ((ch ^ (lo & 7)) * 16));
      half8 vf1 = *reinterpret_cast<const half8*>(vb2 + (lo + 32) * 128 + ((ch ^ (lo & 7)) * 16));
      o0 = __builtin_amdgcn_mfma_f32_32x32x16_f16(vf0, pf, o0, 0, 0, 0);
      o1 = __builtin_amdgcn_mfma_f32_32x32x16_f16(vf1, pf, o1, 0, 0, 0);
    }
    __builtin_amdgcn_s_setprio(0);

    __builtin_amdgcn_sched_barrier(0);   // no ds_read sink below the barrier
    __builtin_amdgcn_s_barrier();
  }

  float inv = 1.0f / l;
  const int gr = (b * H_ + h) * S_ + qrow;
  _Float16* ob = Opart + ((size_t)sp * NR_ + gr) * 64;
#pragma unroll
  for (int mt = 0; mt < 2; mt++)
#pragma unroll
    for (int rq = 0; rq < 4; rq++) {
      half4 v;
#pragma unroll
      for (int e = 0; e < 4; e++) v[e] = (_Float16)(((mt ? o1 : o0)[4 * rq + e]) * inv);
      *reinterpret_cast<half4*>(ob + 32 * mt + 8 * rq + 4 * hi) = v;
    }
  if (hi == 0) keys[sp * NR_ + gr] = m + __log2f(l);
}

// ---------------------------------------------------------------------------
// Combine the two KV-split halves: out = (w0*O0 + w1*O1)/(w0+w1), wi = 2^keyi
// ---------------------------------------------------------------------------
__global__ __launch_bounds__(256) void flash_combine(const _Float16* __restrict__ Opart,
                                                     const float* __restrict__ keys,
                                                     _Float16* __restrict__ attn_out) {
  const int gr = blockIdx.x * 256 + threadIdx.x;
  const float k0 = keys[gr], k1 = keys[NR_ + gr];
  const float mx = fmaxf(k0, k1);
  const float w0 = __builtin_amdgcn_exp2f(k0 - mx);
  const float w1 = __builtin_amdgcn_exp2f(k1 - mx);
  const float inv = 1.0f / (w0 + w1);
  const float a0 = w0 * inv, a1 = w1 * inv;
  const int bh = gr >> 11, qs = gr & 2047, b = bh >> 4, h = bh & 15;
  const half8* p0 = reinterpret_cast<const half8*>(Opart + (size_t)gr * 64);
  const half8* p1 = reinterpret_cast<const half8*>(Opart + ((size_t)NR_ + gr) * 64);
  half8* ob = reinterpret_cast<half8*>(
      attn_out + ((size_t)(b * S_ + qs)) * D_ + h * 64);
#pragma unroll
  for (int j = 0; j < 8; j++) {
    half8 x0 = p0[j], x1 = p1[j];
    half8 o;
#pragma unroll
    for (int e = 0; e < 8; e++)
      o[e] = (_Float16)(a0 * (float)x0[e] + a1 * (float)x1[e]);
    ob[j] = o;
  }
}

// ---------------------------------------------------------------------------
extern "C" void kernel_launch(void* const* d_in, const int* in_sizes, int n_in,
                              void* d_out, int out_size, void* d_ws, size_t ws_size,
                              hipStream_t stream) {
  const float* x     = (const float*)d_in[0];
  const float* W_qkv = (const float*)d_in[1];
  const float* b_qkv = (const float*)d_in[2];
  const float* W_out = (const float*)d_in[3];
  const float* b_out = (const float*)d_in[4];
  float* out = (float*)d_out;

  _Float16* xh    = (_Float16*)d_ws;
  _Float16* qkvh  = xh + (size_t)M_ * D_;
  _Float16* Vth   = qkvh + (size_t)M_ * 3 * D_;
  _Float16* WoT   = Vth + (size_t)B_ * H_ * 64 * S_;
  _Float16* WqT   = WoT + (size_t)D_ * D_;
  _Float16* Opart = WqT;                                  // alias (WqT dead by flash)
  float*    keys  = (float*)(Opart + (size_t)2 * NR_ * 64);
  _Float16* atth  = xh;                                   // alias (xh dead by combine)

  cast_f32_f16<<<(M_ * D_ / 8 + 255) / 256, 256, 0, stream>>>(x, xh, M_ * D_ / 8);
  transpose_cast2<<<dim3(3 * D_ / 64, D_ / 64, 2), 256, 0, stream>>>(
      W_qkv, WqT, W_out, WoT);

  gemm256_mfma<<<256, 512, 114688, stream>>>(
      xh, WqT, b_qkv, qkvh, M_, 3 * D_, D_, QSCALE, D_);

  v_transpose<<<dim3(S_ / 64, B_ * H_), 256, 0, stream>>>(qkvh, Vth);

  flash_mfma<<<dim3(S_ / 128, H_, B_ * 2), 256, 0, stream>>>(qkvh, Vth, Opart, keys);

  flash_combine<<<NR_ / 256, 256, 0, stream>>>(Opart, keys, atth);

  gemm128_mfma<<<256, 256, 65536, stream>>>(
      atth, WoT, b_out, out, M_, D_, D_);
}

// Round 15
// 124.884 us; speedup vs baseline: 1.3500x; 1.0105x over previous
//
#include <hip/hip_runtime.h>

typedef _Float16 half8  __attribute__((ext_vector_type(8)));
typedef _Float16 half4  __attribute__((ext_vector_type(4)));
typedef float    floatx4  __attribute__((ext_vector_type(4)));
typedef float    floatx16 __attribute__((ext_vector_type(16)));
typedef unsigned int uint4v __attribute__((ext_vector_type(4)));

constexpr int B_ = 2, S_ = 2048, D_ = 1024, H_ = 16, M_ = 4096;
constexpr int NR_ = B_ * H_ * S_;               // 65536 (b,h,s) rows
constexpr float QSCALE = 0.18033688011112042f;  // log2(e)/8
constexpr int KVB = 64;                         // kv tile
constexpr int HT = 16;                          // tiles per half (1024/64)

__device__ __forceinline__ void gload16(const void* g, void* l) {
  __builtin_amdgcn_global_load_lds((const __attribute__((address_space(1))) void*)g,
                                   (__attribute__((address_space(3))) void*)l, 16, 0, 0);
}

// ---------------------------------------------------------------------------
// cast fp32 -> fp16, 8 elems/thread
// ---------------------------------------------------------------------------
__global__ __launch_bounds__(256) void cast_f32_f16(const float* __restrict__ in,
                                                    _Float16* __restrict__ out, int n8) {
  int i = blockIdx.x * 256 + threadIdx.x;
  if (i >= n8) return;
  float4 a = reinterpret_cast<const float4*>(in)[2 * i];
  float4 b = reinterpret_cast<const float4*>(in)[2 * i + 1];
  half8 h;
  h[0] = (_Float16)a.x; h[1] = (_Float16)a.y; h[2] = (_Float16)a.z; h[3] = (_Float16)a.w;
  h[4] = (_Float16)b.x; h[5] = (_Float16)b.y; h[6] = (_Float16)b.z; h[7] = (_Float16)b.w;
  reinterpret_cast<half8*>(out)[i] = h;
}

// ---------------------------------------------------------------------------
// W[K][N] fp32 -> WT[N][K] fp16 (64x64 tiles). z selects {W_qkv, W_out}.
// ---------------------------------------------------------------------------
__global__ __launch_bounds__(256) void transpose_cast2(const float* __restrict__ W0,
                                                       _Float16* __restrict__ WT0,
                                                       const float* __restrict__ W1,
                                                       _Float16* __restrict__ WT1) {
  __shared__ float Ws[64][65];
  const int z = blockIdx.z;
  const int NW = z ? D_ : 3 * D_;
  if (blockIdx.x * 64 >= NW) return;
  const float* W = z ? W1 : W0;
  _Float16* WT = z ? WT1 : WT0;
  const int K = D_, N = NW;
  const int n0 = blockIdx.x * 64, k0 = blockIdx.y * 64;
  const int t = threadIdx.x;
#pragma unroll
  for (int i = 0; i < 4; i++) {
    int idx = t + 256 * i;
    int r = idx >> 4, c4 = idx & 15;
    float4 v = *reinterpret_cast<const float4*>(W + (size_t)(k0 + r) * N + n0 + c4 * 4);
    Ws[r][c4 * 4 + 0] = v.x; Ws[r][c4 * 4 + 1] = v.y;
    Ws[r][c4 * 4 + 2] = v.z; Ws[r][c4 * 4 + 3] = v.w;
  }
  __syncthreads();
#pragma unroll
  for (int i = 0; i < 2; i++) {
    int idx = t + 256 * i;
    int r = idx >> 3, ck = idx & 7;
    half8 h;
#pragma unroll
    for (int j = 0; j < 8; j++) h[j] = (_Float16)Ws[ck * 8 + j][r];
    *reinterpret_cast<half8*>(WT + (size_t)(n0 + r) * K + k0 + ck * 8) = h;
  }
}

// ---------------------------------------------------------------------------
// 256x192 fp16 MFMA GEMM (R14 wave-tiling), fine-interleaved staging.
// R15: epilogue ALSO writes the V slice (cols >= 2D) transposed into Vt —
// replaces the standalone v_transpose kernel (saves 16 MB traffic + launch).
// Per wave per d-row the epilogue covers 64 consecutive s -> full 128 B L2
// lines, clean write coalescing. Predicate col>=2048 is wave-uniform per
// n-frag (boundary % 16 == 0). Stores sit after all barriers: no sync change.
// ---------------------------------------------------------------------------
__global__ __launch_bounds__(512, 2) void gemm256_mfma(
    const _Float16* __restrict__ A, const _Float16* __restrict__ BT,
    const float* __restrict__ bias, _Float16* __restrict__ Cout,
    _Float16* __restrict__ Vt,
    int M, int N, int K, float scale_lo, int ncut) {
  extern __shared__ char smem[];   // 114688 B: As[2][32K] | Bs[2][24K]
  const int tid = threadIdx.x, w = tid >> 6, lane = tid & 63;
  const int wm = w >> 1, wn = w & 1;   // 4 waves down M, 2 across N

  const int nwg = gridDim.x, cpx = nwg >> 3;
  const int wg = (blockIdx.x & 7) * cpx + (blockIdx.x >> 3);
  const int nbx = N / 192;
  const int bx = wg % nbx, by = wg / nbx;
  const int m0 = by * 256, n0 = bx * 192;

  const int NT = K >> 6;

  const int rS = tid >> 3, cS = (tid & 7) ^ (rS & 7);
  const char* Apn = (const char*)(A + (size_t)(m0 + rS) * K + cS * 8);
  const char* Bpn = (const char*)(BT + (size_t)(n0 + rS) * K + cS * 8);
  const size_t strideI = (size_t)64 * K * 2;   // 64 rows per load-slice

  auto stageA1 = [&](int buf, int i) {
    gload16(Apn + i * strideI, smem + buf * 32768 + tid * 16 + i * 8192);
  };
  auto stageB1 = [&](int buf, int i) {
    gload16(Bpn + i * strideI, smem + 65536 + buf * 24576 + tid * 16 + i * 8192);
  };

  floatx4 acc[4][6] = {};

#pragma unroll
  for (int i = 0; i < 4; i++) stageA1(0, i);
#pragma unroll
  for (int i = 0; i < 3; i++) stageB1(0, i);
  Apn += 128; Bpn += 128;

  for (int kt = 0; kt < NT; ++kt) {
    const int p = kt & 1;
    asm volatile("s_waitcnt vmcnt(0)" ::: "memory");
    __builtin_amdgcn_s_barrier();
    __builtin_amdgcn_sched_barrier(0);   // no ds_read hoist above the barrier

    const char* Ab = smem + p * 32768;
    const char* Bb = smem + 65536 + p * 24576;
    const bool more = (kt + 1 < NT);

    half8 bf[6][2];
#pragma unroll
    for (int n = 0; n < 6; n++)
#pragma unroll
      for (int ks = 0; ks < 2; ks++) {
        int row = wn * 96 + n * 16 + (lane & 15);
        int ch = (ks * 4 + (lane >> 4)) ^ (row & 7);
        bf[n][ks] = *reinterpret_cast<const half8*>(Bb + row * 128 + ch * 16);
      }

#pragma unroll
    for (int q = 0; q < 4; q++) {
      half8 af[2];
#pragma unroll
      for (int ks = 0; ks < 2; ks++) {
        int row = wm * 64 + q * 16 + (lane & 15);
        int ch = (ks * 4 + (lane >> 4)) ^ (row & 7);
        af[ks] = *reinterpret_cast<const half8*>(Ab + row * 128 + ch * 16);
      }
      if (more) {
        if (q == 0)      { stageA1(p ^ 1, 0); stageA1(p ^ 1, 1); }
        else if (q == 1) { stageA1(p ^ 1, 2); stageA1(p ^ 1, 3); }
        else if (q == 2) { stageB1(p ^ 1, 0); stageB1(p ^ 1, 1); }
        else             { stageB1(p ^ 1, 2); }
      }
      __builtin_amdgcn_s_setprio(1);
#pragma unroll
      for (int ks = 0; ks < 2; ks++)
#pragma unroll
        for (int n = 0; n < 6; n++)
          acc[q][n] = __builtin_amdgcn_mfma_f32_16x16x32_f16(
              af[ks], bf[n][ks], acc[q][n], 0, 0, 0);
      __builtin_amdgcn_s_setprio(0);
    }
    Apn += 128; Bpn += 128;
    __builtin_amdgcn_sched_barrier(0);   // no ds_read sink below the barrier
    __builtin_amdgcn_s_barrier();
  }

#pragma unroll
  for (int mf = 0; mf < 4; mf++)
#pragma unroll
    for (int n = 0; n < 6; n++) {
      int col = n0 + wn * 96 + n * 16 + (lane & 15);
      float bv = bias[col];
      float sc = (col < ncut) ? scale_lo : 1.0f;
      int row0 = m0 + wm * 64 + mf * 16 + (lane >> 4) * 4;
      half4 hv;
#pragma unroll
      for (int reg = 0; reg < 4; reg++) {
        float v = (acc[mf][n][reg] + bv) * sc;
        _Float16 hvv = (_Float16)v;
        Cout[(size_t)(row0 + reg) * N + col] = hvv;
        hv[reg] = hvv;
      }
      // fused V-transpose: col in [2D, 3D) -> Vt[(b*H+h)*64 + d][s0..s0+3]
      if (col >= 2 * D_) {
        int d = col - 2 * D_;                       // 0..1023
        int bb = row0 >> 11, s0 = row0 & 2047;      // quad never crosses b
        _Float16* vt = Vt + ((size_t)(bb * H_ + (d >> 6)) * 64 + (d & 63)) * S_ + s0;
        *reinterpret_cast<half4*>(vt) = hv;
      }
    }
}

// ---------------------------------------------------------------------------
// 128x128 fp16 MFMA GEMM (output projection), fine-interleaved, fp32 out.
// ---------------------------------------------------------------------------
__global__ __launch_bounds__(256, 2) void gemm128_mfma(
    const _Float16* __restrict__ A, const _Float16* __restrict__ BT,
    const float* __restrict__ bias, float* __restrict__ Cout,
    int M, int N, int K) {
  extern __shared__ char smem[];   // 65536 B: As[2][16K] | Bs[2][16K]
  const int tid = threadIdx.x, w = tid >> 6, lane = tid & 63;
  const int wm = w >> 1, wn = w & 1;

  const int nwg = gridDim.x, cpx = nwg >> 3;
  const int wg = (blockIdx.x & 7) * cpx + (blockIdx.x >> 3);
  const int nbx = N >> 7;
  const int bx = wg % nbx, by = wg / nbx;
  const int m0 = by * 128, n0 = bx * 128;

  const int NT = K >> 6;

  const int rS = tid >> 3, cS = (tid & 7) ^ (rS & 7);
  const char* Apn = (const char*)(A + (size_t)(m0 + rS) * K + cS * 8);
  const char* Bpn = (const char*)(BT + (size_t)(n0 + rS) * K + cS * 8);
  const size_t strideI = (size_t)32 * K * 2;   // 32 rows per load-slice

  auto stageA1 = [&](int buf, int i) {
    gload16(Apn + i * strideI, smem + buf * 16384 + tid * 16 + i * 4096);
  };
  auto stageB1 = [&](int buf, int i) {
    gload16(Bpn + i * strideI, smem + 32768 + buf * 16384 + tid * 16 + i * 4096);
  };

  floatx4 acc[4][4] = {};

#pragma unroll
  for (int i = 0; i < 4; i++) stageA1(0, i);
#pragma unroll
  for (int i = 0; i < 4; i++) stageB1(0, i);
  Apn += 128; Bpn += 128;

  for (int kt = 0; kt < NT; ++kt) {
    const int p = kt & 1;
    asm volatile("s_waitcnt vmcnt(0)" ::: "memory");
    __builtin_amdgcn_s_barrier();
    __builtin_amdgcn_sched_barrier(0);

    const char* Ab = smem + p * 16384;
    const char* Bb = smem + 32768 + p * 16384;
    const bool more = (kt + 1 < NT);

    half8 bf[4][2];
#pragma unroll
    for (int n = 0; n < 4; n++)
#pragma unroll
      for (int ks = 0; ks < 2; ks++) {
        int row = wn * 64 + n * 16 + (lane & 15);
        int ch = (ks * 4 + (lane >> 4)) ^ (row & 7);
        bf[n][ks] = *reinterpret_cast<const half8*>(Bb + row * 128 + ch * 16);
      }

#pragma unroll
    for (int q = 0; q < 4; q++) {
      half8 af[2];
#pragma unroll
      for (int ks = 0; ks < 2; ks++) {
        int row = wm * 64 + q * 16 + (lane & 15);
        int ch = (ks * 4 + (lane >> 4)) ^ (row & 7);
        af[ks] = *reinterpret_cast<const half8*>(Ab + row * 128 + ch * 16);
      }
      if (more) {
        if (q == 0)      { stageA1(p ^ 1, 0); stageA1(p ^ 1, 1); }
        else if (q == 1) { stageA1(p ^ 1, 2); stageA1(p ^ 1, 3); }
        else if (q == 2) { stageB1(p ^ 1, 0); stageB1(p ^ 1, 1); }
        else             { stageB1(p ^ 1, 2); stageB1(p ^ 1, 3); }
      }
      __builtin_amdgcn_s_setprio(1);
#pragma unroll
      for (int ks = 0; ks < 2; ks++)
#pragma unroll
        for (int n = 0; n < 4; n++)
          acc[q][n] = __builtin_amdgcn_mfma_f32_16x16x32_f16(
              af[ks], bf[n][ks], acc[q][n], 0, 0, 0);
      __builtin_amdgcn_s_setprio(0);
    }
    Apn += 128; Bpn += 128;
    __builtin_amdgcn_sched_barrier(0);
    __builtin_amdgcn_s_barrier();
  }

#pragma unroll
  for (int q = 0; q < 4; q++)
#pragma unroll
    for (int n = 0; n < 4; n++) {
      int col = n0 + wn * 64 + n * 16 + (lane & 15);
      float bv = bias[col];
#pragma unroll
      for (int reg = 0; reg < 4; reg++) {
        int row = m0 + wm * 64 + q * 16 + (lane >> 4) * 4 + reg;
        Cout[(size_t)row * N + col] = acc[q][n][reg] + bv;
      }
    }
}

// ---------------------------------------------------------------------------
// Flash attention — R13 structure (near trans-bound floor for D=64).
// ---------------------------------------------------------------------------
__global__ __launch_bounds__(256, 4) void flash_mfma(const _Float16* __restrict__ qkv,
                                                     const _Float16* __restrict__ Vt,
                                                     _Float16* __restrict__ Opart,
                                                     float* __restrict__ keys) {
  const int qt = blockIdx.x, h = blockIdx.y;
  const int b = blockIdx.z >> 1, sp = blockIdx.z & 1;
  const int t = threadIdx.x, w = t >> 6, lane = t & 63;
  const int lo = lane & 31, hi = lane >> 5;

  __shared__ _Float16 Ks[2][KVB * 64];    // [kk][d] rows 128B, chunk^(r&7)
  __shared__ _Float16 Vts[2][64 * KVB];   // [d][kk] rows 128B, chunk^(r&7)

  const int qrow = qt * 128 + w * 32 + lo;
  const _Float16* qbase = qkv + (size_t)(b * S_ + qrow) * (3 * D_) + h * 64;
  half8 qf[4];
#pragma unroll
  for (int kd = 0; kd < 4; kd++)
    qf[kd] = *reinterpret_cast<const half8*>(qbase + kd * 16 + hi * 8);
  asm volatile("" : "+v"(qf[0]), "+v"(qf[1]), "+v"(qf[2]), "+v"(qf[3]));

  const size_t kbase = (size_t)(b * S_) * (3 * D_) + D_ + h * 64;
  const size_t vbase = (size_t)(b * H_ + h) * 64 * S_;
  const int kvbase = sp * (S_ / 2);

  const int rs = t >> 3, cs = (t & 7) ^ (rs & 7);
  const char* kp = (const char*)(qkv + kbase + (size_t)(kvbase + rs) * (3 * D_) + cs * 8);
  const char* vp = (const char*)(Vt + vbase + (size_t)rs * S_ + kvbase + cs * 8);
  constexpr size_t K_ROW32 = (size_t)32 * 3 * D_ * 2;   // +32 rows in qkv
  constexpr size_t V_ROW32 = (size_t)32 * S_ * 2;       // +32 rows in Vt
  constexpr size_t K_TILE  = (size_t)KVB * 3 * D_ * 2;  // per-tile advance
  constexpr size_t V_TILE  = (size_t)KVB * 2;

  auto stage = [&](int buf) {
    char* kd_ = (char*)&Ks[buf][0] + t * 16;
    char* vd_ = (char*)&Vts[buf][0] + t * 16;
    gload16(kp, kd_);
    gload16(kp + K_ROW32, kd_ + 4096);
    gload16(vp, vd_);
    gload16(vp + V_ROW32, vd_ + 4096);
  };

  floatx16 o0, o1;
#pragma unroll
  for (int r = 0; r < 16; r++) { o0[r] = 0.f; o1[r] = 0.f; }
  float m = -1e30f, l = 0.f;

  stage(0);
  kp += K_TILE; vp += V_TILE;

#pragma unroll 2
  for (int tt = 0; tt < HT; ++tt) {
    const int cb = tt & 1;
    if (tt + 1 < HT) {
      stage(cb ^ 1);
      kp += K_TILE; vp += V_TILE;
      asm volatile("s_waitcnt vmcnt(4)" ::: "memory");
    } else {
      asm volatile("s_waitcnt vmcnt(0)" ::: "memory");
    }
    __builtin_amdgcn_s_barrier();
    __builtin_amdgcn_sched_barrier(0);   // no ds_read hoist above the barrier

    const char* kb2 = (const char*)&Ks[cb][0];
    floatx16 s0v, s1v;
#pragma unroll
    for (int r = 0; r < 16; r++) { s0v[r] = 0.f; s1v[r] = 0.f; }
    __builtin_amdgcn_s_setprio(1);
#pragma unroll
    for (int kd = 0; kd < 4; kd++) {
      int r0 = lo, r1 = 32 + lo;
      half8 k0f = *reinterpret_cast<const half8*>(
          kb2 + r0 * 128 + (((kd * 2 + hi) ^ (r0 & 7)) * 16));
      half8 k1f = *reinterpret_cast<const half8*>(
          kb2 + r1 * 128 + (((kd * 2 + hi) ^ (r1 & 7)) * 16));
      s0v = __builtin_amdgcn_mfma_f32_32x32x16_f16(k0f, qf[kd], s0v, 0, 0, 0);
      s1v = __builtin_amdgcn_mfma_f32_32x32x16_f16(k1f, qf[kd], s1v, 0, 0, 0);
    }
    __builtin_amdgcn_s_setprio(0);

    float tm[16];
#pragma unroll
    for (int r = 0; r < 16; r++) tm[r] = fmaxf(s0v[r], s1v[r]);
    float u0 = fmaxf(fmaxf(tm[0], tm[1]), tm[2]);
    float u1 = fmaxf(fmaxf(tm[3], tm[4]), tm[5]);
    float u2 = fmaxf(fmaxf(tm[6], tm[7]), tm[8]);
    float u3 = fmaxf(fmaxf(tm[9], tm[10]), tm[11]);
    float u4 = fmaxf(fmaxf(tm[12], tm[13]), tm[14]);
    float pm = fmaxf(fmaxf(u0, u1), u2);
    pm = fmaxf(fmaxf(pm, u3), u4);
    pm = fmaxf(pm, tm[15]);
    pm = fmaxf(pm, __shfl_xor(pm, 32));
    if (!__all(pm <= m + 8.0f)) {
      float mn = fmaxf(m, pm);
      float al = __builtin_amdgcn_exp2f(m - mn);
      m = mn; l *= al;
#pragma unroll
      for (int r = 0; r < 16; r++) { o0[r] *= al; o1[r] *= al; }
    }
    float rr[16];
#pragma unroll
    for (int r = 0; r < 16; r++) {
      s0v[r] = __builtin_amdgcn_exp2f(s0v[r] - m);
      s1v[r] = __builtin_amdgcn_exp2f(s1v[r] - m);
      rr[r] = s0v[r] + s1v[r];
    }
#pragma unroll
    for (int st = 8; st >= 1; st >>= 1)
#pragma unroll
      for (int r = 0; r < st; r++) rr[r] += rr[r + st];
    float rs2 = rr[0];
    rs2 += __shfl_xor(rs2, 32);
    l += rs2;

    half8 pf0a, pf0b, pf1a, pf1b;
    {
      unsigned a0 = __builtin_bit_cast(unsigned, __builtin_amdgcn_cvt_pkrtz(s0v[0], s0v[1]));
      unsigned b0 = __builtin_bit_cast(unsigned, __builtin_amdgcn_cvt_pkrtz(s0v[4], s0v[5]));
      unsigned a1 = __builtin_bit_cast(unsigned, __builtin_amdgcn_cvt_pkrtz(s0v[2], s0v[3]));
      unsigned b1 = __builtin_bit_cast(unsigned, __builtin_amdgcn_cvt_pkrtz(s0v[6], s0v[7]));
      asm("v_permlane32_swap_b32 %0, %1" : "+v"(a0), "+v"(b0));
      asm("v_permlane32_swap_b32 %0, %1" : "+v"(a1), "+v"(b1));
      uint4v u; u[0] = a0; u[1] = a1; u[2] = b0; u[3] = b1;
      pf0a = __builtin_bit_cast(half8, u);
      a0 = __builtin_bit_cast(unsigned, __builtin_amdgcn_cvt_pkrtz(s0v[8], s0v[9]));
      b0 = __builtin_bit_cast(unsigned, __builtin_amdgcn_cvt_pkrtz(s0v[12], s0v[13]));
      a1 = __builtin_bit_cast(unsigned, __builtin_amdgcn_cvt_pkrtz(s0v[10], s0v[11]));
      b1 = __builtin_bit_cast(unsigned, __builtin_amdgcn_cvt_pkrtz(s0v[14], s0v[15]));
      asm("v_permlane32_swap_b32 %0, %1" : "+v"(a0), "+v"(b0));
      asm("v_permlane32_swap_b32 %0, %1" : "+v"(a1), "+v"(b1));
      u[0] = a0; u[1] = a1; u[2] = b0; u[3] = b1;
      pf0b = __builtin_bit_cast(half8, u);
      a0 = __builtin_bit_cast(unsigned, __builtin_amdgcn_cvt_pkrtz(s1v[0], s1v[1]));
      b0 = __builtin_bit_cast(unsigned, __builtin_amdgcn_cvt_pkrtz(s1v[4], s1v[5]));
      a1 = __builtin_bit_cast(unsigned, __builtin_amdgcn_cvt_pkrtz(s1v[2], s1v[3]));
      b1 = __builtin_bit_cast(unsigned, __builtin_amdgcn_cvt_pkrtz(s1v[6], s1v[7]));
      asm("v_permlane32_swap_b32 %0, %1" : "+v"(a0), "+v"(b0));
      asm("v_permlane32_swap_b32 %0, %1" : "+v"(a1), "+v"(b1));
      u[0] = a0; u[1] = a1; u[2] = b0; u[3] = b1;
      pf1a = __builtin_bit_cast(half8, u);
      a0 = __builtin_bit_cast(unsigned, __builtin_amdgcn_cvt_pkrtz(s1v[8], s1v[9]));
      b0 = __builtin_bit_cast(unsigned, __builtin_amdgcn_cvt_pkrtz(s1v[12], s1v[13]));
      a1 = __builtin_bit_cast(unsigned, __builtin_amdgcn_cvt_pkrtz(s1v[10], s1v[11]));
      b1 = __builtin_bit_cast(unsigned, __builtin_amdgcn_cvt_pkrtz(s1v[14], s1v[15]));
      asm("v_permlane32_swap_b32 %0, %1" : "+v"(a0), "+v"(b0));
      asm("v_permlane32_swap_b32 %0, %1" : "+v"(a1), "+v"(b1));
      u[0] = a0; u[1] = a1; u[2] = b0; u[3] = b1;
      pf1b = __builtin_bit_cast(half8, u);
    }

    const char* vb2 = (const char*)&Vts[cb][0];
    __builtin_amdgcn_s_setprio(1);
#pragma unroll
    for (int ks = 0; ks < 4; ks++) {
      half8 pf = (ks == 0) ? pf0a : (ks == 1) ? pf0b : (ks == 2) ? pf1a : pf1b;
      const int ch = ks * 2 + hi;
      half8 vf0 = *reinterpret_cast<const half8*>(vb2 + lo * 128 + ((ch ^ (lo & 7)) * 16));
      half8 vf1 = *reinterpret_cast<const half8*>(vb2 + (lo + 32) * 128 + ((ch ^ (lo & 7)) * 16));
      o0 = __builtin_amdgcn_mfma_f32_32x32x16_f16(vf0, pf, o0, 0, 0, 0);
      o1 = __builtin_amdgcn_mfma_f32_32x32x16_f16(vf1, pf, o1, 0, 0, 0);
    }
    __builtin_amdgcn_s_setprio(0);

    __builtin_amdgcn_sched_barrier(0);   // no ds_read sink below the barrier
    __builtin_amdgcn_s_barrier();
  }

  float inv = 1.0f / l;
  const int gr = (b * H_ + h) * S_ + qrow;
  _Float16* ob = Opart + ((size_t)sp * NR_ + gr) * 64;
#pragma unroll
  for (int mt = 0; mt < 2; mt++)
#pragma unroll
    for (int rq = 0; rq < 4; rq++) {
      half4 v;
#pragma unroll
      for (int e = 0; e < 4; e++) v[e] = (_Float16)(((mt ? o1 : o0)[4 * rq + e]) * inv);
      *reinterpret_cast<half4*>(ob + 32 * mt + 8 * rq + 4 * hi) = v;
    }
  if (hi == 0) keys[sp * NR_ + gr] = m + __log2f(l);
}

// ---------------------------------------------------------------------------
// Combine the two KV-split halves: out = (w0*O0 + w1*O1)/(w0+w1), wi = 2^keyi
// ---------------------------------------------------------------------------
__global__ __launch_bounds__(256) void flash_combine(const _Float16* __restrict__ Opart,
                                                     const float* __restrict__ keys,
                                                     _Float16* __restrict__ attn_out) {
  const int gr = blockIdx.x * 256 + threadIdx.x;
  const float k0 = keys[gr], k1 = keys[NR_ + gr];
  const float mx = fmaxf(k0, k1);
  const float w0 = __builtin_amdgcn_exp2f(k0 - mx);
  const float w1 = __builtin_amdgcn_exp2f(k1 - mx);
  const float inv = 1.0f / (w0 + w1);
  const float a0 = w0 * inv, a1 = w1 * inv;
  const int bh = gr >> 11, qs = gr & 2047, b = bh >> 4, h = bh & 15;
  const half8* p0 = reinterpret_cast<const half8*>(Opart + (size_t)gr * 64);
  const half8* p1 = reinterpret_cast<const half8*>(Opart + ((size_t)NR_ + gr) * 64);
  half8* ob = reinterpret_cast<half8*>(
      attn_out + ((size_t)(b * S_ + qs)) * D_ + h * 64);
#pragma unroll
  for (int j = 0; j < 8; j++) {
    half8 x0 = p0[j], x1 = p1[j];
    half8 o;
#pragma unroll
    for (int e = 0; e < 8; e++)
      o[e] = (_Float16)(a0 * (float)x0[e] + a1 * (float)x1[e]);
    ob[j] = o;
  }
}

// ---------------------------------------------------------------------------
extern "C" void kernel_launch(void* const* d_in, const int* in_sizes, int n_in,
                              void* d_out, int out_size, void* d_ws, size_t ws_size,
                              hipStream_t stream) {
  const float* x     = (const float*)d_in[0];
  const float* W_qkv = (const float*)d_in[1];
  const float* b_qkv = (const float*)d_in[2];
  const float* W_out = (const float*)d_in[3];
  const float* b_out = (const float*)d_in[4];
  float* out = (float*)d_out;

  _Float16* xh    = (_Float16*)d_ws;
  _Float16* qkvh  = xh + (size_t)M_ * D_;
  _Float16* Vth   = qkvh + (size_t)M_ * 3 * D_;
  _Float16* WoT   = Vth + (size_t)B_ * H_ * 64 * S_;
  _Float16* WqT   = WoT + (size_t)D_ * D_;
  _Float16* Opart = WqT;                                  // alias (WqT dead by flash)
  float*    keys  = (float*)(Opart + (size_t)2 * NR_ * 64);
  _Float16* atth  = xh;                                   // alias (xh dead by combine)

  cast_f32_f16<<<(M_ * D_ / 8 + 255) / 256, 256, 0, stream>>>(x, xh, M_ * D_ / 8);
  transpose_cast2<<<dim3(3 * D_ / 64, D_ / 64, 2), 256, 0, stream>>>(
      W_qkv, WqT, W_out, WoT);

  // QKV projection with fused V-transpose (v_transpose kernel eliminated)
  gemm256_mfma<<<256, 512, 114688, stream>>>(
      xh, WqT, b_qkv, qkvh, Vth, M_, 3 * D_, D_, QSCALE, D_);

  flash_mfma<<<dim3(S_ / 128, H_, B_ * 2), 256, 0, stream>>>(qkvh, Vth, Opart, keys);

  flash_combine<<<NR_ / 256, 256, 0, stream>>>(Opart, keys, atth);

  gemm128_mfma<<<256, 256, 65536, stream>>>(
      atth, WoT, b_out, out, M_, D_, D_);
}